// Round 10
// baseline (771.298 us; speedup 1.0000x reference)
//
#include <hip/hip_runtime.h>
#include <hip/hip_bf16.h>

typedef unsigned short bf16_t;
typedef __bf16 bf16x8 __attribute__((ext_vector_type(8)));
typedef float f32x4 __attribute__((ext_vector_type(4)));

__device__ __forceinline__ unsigned short f2bf(float x){
  union { __hip_bfloat16 h; unsigned short u; } c;
  c.h = __float2bfloat16(x);
  return c.u;
}
__device__ __forceinline__ float bf2f(bf16_t u){
  union { unsigned short u; __hip_bfloat16 h; } c;
  c.u = u;
  return __bfloat162float(c.h);
}

#define GL2L(g, l) __builtin_amdgcn_global_load_lds( \
    (const __attribute__((address_space(1))) unsigned int*)(g), \
    (__attribute__((address_space(3))) unsigned int*)(l), 16, 0, 0)

// ---------------------------------------------------------------------------
// bf16 MFMA GEMM, 128x256 (MxN) tile, BK=32, 8 waves (2M x 4N) x 64x64 out,
// 512 threads. 3-deep pipelined K-loop (72 KB LDS): counted vmcnt (3/0), one
// raw s_barrier per step, stage(t+2) right after the barrier. Each wave
// stages 1KB of A (1 GL2L) + 2KB of B (2 GL2L) per step, 16B/lane,
// XOR-swizzled (c ^= (row>>1)&3) on both GL2L source and ds_read.
// MAP=0: blockIdx=(col,row,ks) | MAP=1: blockIdx=(ks,col,row) -> id%8=ks |
// MAP=2: col = y*8 + x (id%8 = col%8, exit if col*256>=N), z=row, ks=0.
// ACT: 0 = f32 partial store at ks*csplit; 4 = bf16 store with bias.
// ---------------------------------------------------------------------------
template<int ACT, int MAP>
__global__ __launch_bounds__(512)
void gemm_bf16(const bf16_t* __restrict__ A, int lda,
               const bf16_t* __restrict__ Bt, int ldb,
               float* __restrict__ C, int ldc, size_t csplit,
               const float* __restrict__ bias,
               int M, int N, int K, int Kchunk)
{
  __shared__ __align__(16) bf16_t As[3][128*32];   // 3 x 8KB
  __shared__ __align__(16) bf16_t Bs[3][256*32];   // 3 x 16KB
  const int tid = threadIdx.x;
  const int w = tid >> 6, lane = tid & 63;
  const int wm = w >> 2, wn = w & 3;
  const int lr = lane & 15, kq = lane >> 4;
  int bcol, brow, bks;
  if (MAP == 0)      { bcol = blockIdx.x; brow = blockIdx.y; bks = blockIdx.z; }
  else if (MAP == 1) { bks = blockIdx.x;  bcol = blockIdx.y; brow = blockIdx.z; }
  else {
    bcol = blockIdx.y*8 + blockIdx.x; brow = blockIdx.z; bks = 0;
    if (bcol*256 >= N) return;
  }
  const int gm0 = brow * 128, gn0 = bcol * 256;
  const int k0 = bks * Kchunk;
  const int nt = (min(k0 + Kchunk, K) - k0) >> 5;   // K-tiles (mult of 32)

  // staging: wave w owns A rows [w*16, w*16+16) (1 GL2L) and B rows
  // [w*32, w*32+32) (2 GL2L); lane l -> row l/4, 16B-unit (l%4)^((row>>1)&3)
  const int srow = lane >> 2;
  const int scol = ((lane & 3) ^ ((srow >> 1) & 3)) << 3;   // element offset
  const int am0 = min(gm0 + w*16 + srow,      M-1);
  const int bn0 = min(gn0 + w*32 + srow,      N-1);
  const int bn1 = min(gn0 + w*32 + 16 + srow, N-1);
  const bf16_t* Ag0 = A  + (size_t)am0*lda + scol;
  const bf16_t* Bg0 = Bt + (size_t)bn0*ldb + scol;
  const bf16_t* Bg1 = Bt + (size_t)bn1*ldb + scol;

  auto STAGEF = [&](int t, int slot) {
    const int kk = k0 + (t << 5);
    char* al = (char*)(&As[slot][0]) + w*1024;
    char* bl = (char*)(&Bs[slot][0]) + w*2048;
    GL2L(Ag0 + kk, al);
    GL2L(Bg0 + kk, bl);
    GL2L(Bg1 + kk, bl + 1024);
  };

  STAGEF(0, 0);
  if (nt > 1) STAGEF(1, 1);

  const int kqs = kq ^ ((lr >> 1) & 3);     // swizzled 16B col for frag reads
  f32x4 acc[4][4] = {};

  int cs = 0;                               // LDS slot of tile t
  for (int t = 0; t < nt; ++t) {
    if (nt - t >= 2) { asm volatile("s_waitcnt vmcnt(3)" ::: "memory"); }
    else             { asm volatile("s_waitcnt vmcnt(0)" ::: "memory"); }
    __builtin_amdgcn_s_barrier();           // tile t in LDS, tile t-1 consumed
    __builtin_amdgcn_sched_barrier(0);
    if (t + 2 < nt) {
      const int s2 = (cs >= 1) ? cs - 1 : cs + 2;   // (cs+2)%3
      STAGEF(t + 2, s2);                    // overwrites tile t-1's slot
    }
    const char* Ab = (const char*)(&As[cs][0]);
    const char* Bb = (const char*)(&Bs[cs][0]);
    bf16x8 af[4], bfr[4];
#pragma unroll
    for (int mi = 0; mi < 4; mi++)
      af[mi] = *(const bf16x8*)(Ab + ((wm*64 + mi*16 + lr) << 6) + (kqs << 4));
#pragma unroll
    for (int ni = 0; ni < 4; ni++)
      bfr[ni] = *(const bf16x8*)(Bb + ((wn*64 + ni*16 + lr) << 6) + (kqs << 4));
    __builtin_amdgcn_s_setprio(1);
#pragma unroll
    for (int mi = 0; mi < 4; mi++)
#pragma unroll
      for (int ni = 0; ni < 4; ni++)
        acc[mi][ni] = __builtin_amdgcn_mfma_f32_16x16x32_bf16(af[mi], bfr[ni], acc[mi][ni], 0, 0, 0);
    __builtin_amdgcn_s_setprio(0);
    __builtin_amdgcn_sched_barrier(0);
    cs = (cs == 2) ? 0 : cs + 1;
  }

  // epilogue: D row = kq*4 + i, col = lane&15 per 16x16 frag
#pragma unroll
  for (int mi = 0; mi < 4; mi++) {
#pragma unroll
    for (int ni = 0; ni < 4; ni++) {
      const int col = gn0 + wn*64 + ni*16 + lr;
      const float bv = (ACT == 4) ? bias[col] : 0.f;
#pragma unroll
      for (int i = 0; i < 4; i++) {
        const int row = gm0 + wm*64 + mi*16 + kq*4 + i;
        if (row < M) {
          const float v = acc[mi][ni][i] + bv;
          if (ACT == 4) ((bf16_t*)C)[(size_t)row*ldc + col] = f2bf(v);
          else C[(size_t)bks*csplit + (size_t)row*ldc + col] = v;
        }
      }
    }
  }
}

// sum split-K partials, add bias, write prop f32 + X right half bf16
__global__ void reduce_compress(const float* __restrict__ part, const float* __restrict__ bias,
                                float* __restrict__ prop, bf16_t* __restrict__ xr)
{
  const int idx = blockIdx.x*256 + threadIdx.x;   // < 921600
  const int m = idx >> 10, d = idx & 1023;
  float v = bias[d];
#pragma unroll
  for (int z = 0; z < 8; z++) v += part[(size_t)z*921600 + idx];
  prop[idx] = v;
  xr[(size_t)m*2048 + 1024 + d] = f2bf(v);
}

// RZ split-4 reduce: v = sigmoid(sum+bias). col<1024: Xh_right = bf16(v*prop)
// (the r path); col>=1024: Zbuf = v (the z path).
__global__ void reduce_rz(const float* __restrict__ part, const float* __restrict__ bias,
                          const float* __restrict__ prop, float* __restrict__ Zbuf,
                          bf16_t* __restrict__ Xh)
{
  const int idx = blockIdx.x*256 + threadIdx.x;   // < 1843200
  const int m = idx >> 11, c = idx & 2047;
  float v = bias[c];
#pragma unroll
  for (int z = 0; z < 4; z++) v += part[(size_t)z*1843200 + idx];
  v = 1.f / (1.f + __expf(-v));
  if (c < 1024) Xh[(size_t)m*2048 + 1024 + c] = f2bf(v * prop[(size_t)m*1024 + c]);
  else          Zbuf[(size_t)m*1024 + (c - 1024)] = v;
}

// h split-8 reduce: h_hat = tanh(sum+bh); prop = (1-z)*prop + z*h_hat;
// also write X right half bf16.
__global__ void reduce_h(const float* __restrict__ part, const float* __restrict__ bias,
                         const float* __restrict__ Zbuf, float* __restrict__ prop,
                         bf16_t* __restrict__ X)
{
  const int idx = blockIdx.x*256 + threadIdx.x;   // < 921600
  const int m = idx >> 10, d = idx & 1023;
  float v = bias[d];
#pragma unroll
  for (int z = 0; z < 8; z++) v += part[(size_t)z*921600 + idx];
  v = tanhf(v);
  const float zz = Zbuf[idx];
  const float pn = (1.f - zz)*prop[idx] + zz*v;
  prop[idx] = pn;
  X[(size_t)m*2048 + 1024 + d] = f2bf(pn);
}

// u_row[e][h] = sum_d W_edge[e][h][d]*W_att[e][d]; u_col with W_att[e][1024+d]
__global__ void compute_u(const float* __restrict__ We, const float* __restrict__ Wa,
                          float* __restrict__ u_row, float* __restrict__ u_col)
{
  const int w = threadIdx.x >> 6, lane = threadIdx.x & 63;
  const int idx = blockIdx.x*4 + w;               // grid=1792 -> idx<7168
  const int e = idx >> 10, h = idx & 1023;
  const float* wep = We + ((size_t)e*1024 + h)*1024;
  const float* wr  = Wa + (size_t)e*2048;
  const float* wc  = wr + 1024;
  float ar = 0.f, ac = 0.f;
#pragma unroll
  for (int t = 0; t < 16; t++) {
    const float v = wep[lane + 64*t];
    ar += v*wr[lane + 64*t];
    ac += v*wc[lane + 64*t];
  }
  for (int off = 32; off; off >>= 1) { ar += __shfl_down(ar, off); ac += __shfl_down(ac, off); }
  if (lane == 0) { u_row[idx] = ar; u_col[idx] = ac; }
}

// crc[e] = b_edge[e].Wa_row[e], crc[7+e] = b_edge[e].Wa_col[e]
__global__ void crc_kernel(const float* __restrict__ be, const float* __restrict__ Wa,
                           float* __restrict__ crc)
{
  const int w = threadIdx.x >> 6, lane = threadIdx.x & 63;
  for (int idx = w; idx < 14; idx += 4) {
    const int e = idx >> 1, which = idx & 1;
    const float* bp = be + e*1024;
    const float* wp = Wa + (size_t)e*2048 + which*1024;
    float a = 0.f;
#pragma unroll
    for (int t = 0; t < 16; t++) a += bp[lane + 64*t]*wp[lane + 64*t];
    for (int off = 32; off; off >>= 1) a += __shfl_down(a, off);
    if (lane == 0) crc[which*7 + e] = a;
  }
}

// per (b,e): row[n]=prop[b,n,:].u_row[e]; col[n]=prop[b,n,:].u_col[e]
// scores[b,e,i,j] = sigmoid(row[i]+col[j]+b_att[e]+crc_row[e]+crc_col[e])
__global__ void attn_kernel(const float* __restrict__ prop, const float* __restrict__ u_row,
                            const float* __restrict__ u_col, const float* __restrict__ crc,
                            const float* __restrict__ b_att, float* __restrict__ scores)
{
  const int b = blockIdx.x, e = blockIdx.y;
  __shared__ float rowv[15], colv[15];
  const int w = threadIdx.x >> 6, lane = threadIdx.x & 63;
  const float* ur = u_row + (size_t)e*1024;
  const float* uc = u_col + (size_t)e*1024;
  for (int n = w; n < 15; n += 4) {
    const float* pr = prop + (size_t)(b*15 + n)*1024;
    float ar = 0.f, ac = 0.f;
#pragma unroll
    for (int t = 0; t < 16; t++) {
      const float pv = pr[lane + 64*t];
      ar += pv*ur[lane + 64*t];
      ac += pv*uc[lane + 64*t];
    }
    for (int off = 32; off; off >>= 1) { ar += __shfl_down(ar, off); ac += __shfl_down(ac, off); }
    if (lane == 0) { rowv[n] = ar; colv[n] = ac; }
  }
  __syncthreads();
  const float base = b_att[e] + crc[e] + crc[7 + e];
  for (int idx = threadIdx.x; idx < 225; idx += 256) {
    const int i = idx/15, j = idx - i*15;
    const float s = 1.f / (1.f + __expf(-(rowv[i] + colv[j] + base)));
    scores[((size_t)(b*7 + e)*15 + i)*15 + j] = s;
  }
}

// merged[b,i,d] = sum_e sum_j scores[b,e,i,j]*msg[b*15+j, e*1024+d]
// -> X left half AND Xh left half (bf16)
__global__ void merged_kernel(const bf16_t* __restrict__ msg, const float* __restrict__ scores,
                              bf16_t* __restrict__ X, bf16_t* __restrict__ Xh)
{
  const int b = blockIdx.x, c = blockIdx.y;   // c: 128-wide d-chunk, 8 chunks
  __shared__ float ms[15*7*128];              // [j][e][dl]
  __shared__ float sc[1575];                  // [e][i][j]
  for (int q = threadIdx.x; q < 3360; q += 256) {     // 4-wide bf16 loads
    const int idx = q*4;
    const int j = idx / 896;
    const int rem = idx - j*896;
    const int e = rem >> 7, dl = rem & 127;
    const ushort4 v = *(const ushort4*)(msg + (size_t)(b*15 + j)*7168 + e*1024 + c*128 + dl);
    ms[idx]   = bf2f(v.x);
    ms[idx+1] = bf2f(v.y);
    ms[idx+2] = bf2f(v.z);
    ms[idx+3] = bf2f(v.w);
  }
  for (int idx = threadIdx.x; idx < 1575; idx += 256)
    sc[idx] = scores[(size_t)b*1575 + idx];
  __syncthreads();
  for (int oi = threadIdx.x; oi < 1920; oi += 256) {
    const int i = oi >> 7, dl = oi & 127;
    float acc = 0.f;
#pragma unroll
    for (int e = 0; e < 7; e++)
#pragma unroll
      for (int j = 0; j < 15; j++)
        acc += sc[(e*15 + i)*15 + j] * ms[j*896 + e*128 + dl];
    const bf16_t o = f2bf(acc);
    X [(size_t)(b*15 + i)*2048 + c*128 + dl] = o;
    Xh[(size_t)(b*15 + i)*2048 + c*128 + dl] = o;
  }
}

// 64x64-tile transpose f32 -> bf16: out[c][r] = in[r][c]  (dims %64 == 0)
__global__ void transpose_k(const float* __restrict__ in, bf16_t* __restrict__ out,
                            int R, int C, int out_ld, size_t in_batch, size_t out_batch)
{
  __shared__ float t[64][65];
  in  += (size_t)blockIdx.z * in_batch;
  out += (size_t)blockIdx.z * out_batch;
  const int r0 = blockIdx.x*64, c0 = blockIdx.y*64;
  const int tc = threadIdx.x & 63, tr = threadIdx.x >> 6;
#pragma unroll
  for (int i = 0; i < 16; i++) {
    const int r = tr*16 + i;
    t[r][tc] = in[(size_t)(r0 + r)*C + c0 + tc];
  }
  __syncthreads();
#pragma unroll
  for (int i = 0; i < 16; i++) {
    const int rr = tr*16 + i;
    out[(size_t)(c0 + rr)*out_ld + r0 + tc] = f2bf(t[tc][rr]);
  }
}

__global__ void cast_f32_bf16(const float4* __restrict__ in, ushort4* __restrict__ out, int n4)
{
  int i = blockIdx.x*256 + threadIdx.x;
  const int stride = gridDim.x*256;
  for (; i < n4; i += stride) {
    const float4 v = in[i];
    out[i] = make_ushort4(f2bf(v.x), f2bf(v.y), f2bf(v.z), f2bf(v.w));
  }
}

__global__ void cat2_kernel(const float* __restrict__ a, const float* __restrict__ b,
                            float* __restrict__ o)
{
  const int i = blockIdx.x*256 + threadIdx.x;
  if (i < 1024) o[i] = a[i];
  else if (i < 2048) o[i] = b[i - 1024];
}

// final outputs from last-iteration scores
__global__ void finalize_kernel(const float* __restrict__ scores, float* __restrict__ out)
{
  const int b = blockIdx.x;   // 0..59
  __shared__ float sc[1575];
  __shared__ float act[105];
  __shared__ float asum[15];
  __shared__ float t2[7];
  for (int idx = threadIdx.x; idx < 1575; idx += 256)
    sc[idx] = scores[(size_t)b*1575 + idx];
  __syncthreads();
  for (int idx = threadIdx.x; idx < 105; idx += 256) {
    const int i = idx/7, e = idx - i*7;
    float a = 0.f;
#pragma unroll
    for (int j = 0; j < 15; j++)
      a += (1.f - sc[i*15 + j]) * sc[(e*15 + i)*15 + j];
    act[idx] = a;
    out[(size_t)b*105 + idx] = a;
  }
  for (int idx = threadIdx.x; idx < 225; idx += 256) {
    const int i = idx/15, j = idx - i*15;
    out[6660 + (size_t)b*225 + idx] = 1.f - sc[i*15 + j];
  }
  if (threadIdx.x < 15) {
    const int i = threadIdx.x;
    float s = 0.f;
#pragma unroll
    for (int j = 0; j < 15; j++) s += 1.f - sc[i*15 + j];
    asum[i] = s;
  }
  __syncthreads();
  if (threadIdx.x < 7) {
    const int e = threadIdx.x;
    float t = 0.f;
#pragma unroll
    for (int i = 0; i < 15; i++) t += act[i*7 + e]*asum[i];
    t2[e] = t;
  }
  __syncthreads();
  if (threadIdx.x == 0) {
    float mx = -1e30f;
    for (int e = 1; e < 7; e++) mx = fmaxf(mx, t2[e]);
    float s = 0.f, ex[6];
    for (int e = 1; e < 7; e++) { ex[e-1] = __expf(t2[e] - mx); s += ex[e-1]; }
    for (int e = 1; e < 7; e++) out[6300 + (size_t)b*6 + (e-1)] = ex[e-1]/s;
  }
}

extern "C" void kernel_launch(void* const* d_in, const int* in_sizes, int n_in,
                              void* d_out, int out_size, void* d_ws, size_t ws_size,
                              hipStream_t stream)
{
  const float* pose = (const float*)d_in[0];
  const float* Wc   = (const float*)d_in[1];
  const float* bc   = (const float*)d_in[2];
  const float* We   = (const float*)d_in[3];
  const float* be   = (const float*)d_in[4];
  const float* Wa   = (const float*)d_in[5];
  const float* ba   = (const float*)d_in[6];
  const float* Wr   = (const float*)d_in[7];
  const float* br   = (const float*)d_in[8];
  const float* Wz   = (const float*)d_in[9];
  const float* bz   = (const float*)d_in[10];
  const float* Wh   = (const float*)d_in[11];
  const float* bh   = (const float*)d_in[12];
  float* out = (float*)d_out;

  // ---- workspace carving ----
  char* p = (char*)d_ws;
  auto alloc = [&](size_t b) { char* r = p; p += (b + 255) & ~(size_t)255; return r; };
  bf16_t* Wedge_t = (bf16_t*)alloc(7168ull*1024*2);   // [e*1024+d][h]
  bf16_t* Wrz_t   = (bf16_t*)alloc(2048ull*2048*2);   // [n][k]
  bf16_t* Wh_t    = (bf16_t*)alloc(1024ull*2048*2);   // [n][k]
  bf16_t* X       = (bf16_t*)alloc(900ull*2048*2);    // [merged | prop] bf16
  float*  prop    = (float*) alloc(900ull*1024*4);    // f32 master state
  float*  scores  = (float*) alloc(60ull*7*15*15*4);
  float*  u_row   = (float*) alloc(7168*4);
  float*  u_col   = (float*) alloc(7168*4);
  float*  crc     = (float*) alloc(64);
  float*  brzv    = (float*) alloc(2048*4);
  // phase-union region:
  // phase1 (compress): Abf(46.08) + Wct(52.43) + partial(29.49) = 128 MB
  // phase2 (iters): msgb 12.9 | Zbuf 3.7 | Xh 3.7 | partRZ 29.5 | partH 29.5
  char* r1 = alloc(128000000ull);
  bf16_t* Abf     = (bf16_t*)r1;
  bf16_t* Wct     = (bf16_t*)(r1 + 46080000ull);
  float*  partial = (float*) (r1 + 46080000ull + 52428800ull);
  bf16_t* msgb    = (bf16_t*)r1;
  float*  Zbuf    = (float*) (r1 + 12902400ull);
  bf16_t* Xh      = (bf16_t*)(r1 + 16588800ull);
  float*  partRZ  = (float*) (r1 + 20275200ull);      // 4 x 900 x 2048 f32
  float*  partH   = (float*) (r1 + 49766400ull);      // 8 x 900 x 1024 f32

  // ---- precompute ----
  compute_u<<<1792, 256, 0, stream>>>(We, Wa, u_row, u_col);
  crc_kernel<<<1, 256, 0, stream>>>(be, Wa, crc);
  cast_f32_bf16<<<2048, 256, 0, stream>>>((const float4*)pose, (ushort4*)Abf, 23040000/4);
  transpose_k<<<dim3(400,16,1), 256, 0, stream>>>(Wc, Wct, 25600, 1024, 25600, 0, 0);
  transpose_k<<<dim3(16,16,7),  256, 0, stream>>>(We, Wedge_t, 1024, 1024, 1024,
                                                  1024ull*1024, 1024ull*1024);
  transpose_k<<<dim3(32,16,1),  256, 0, stream>>>(Wr, Wrz_t, 2048, 1024, 2048, 0, 0);
  transpose_k<<<dim3(32,16,1),  256, 0, stream>>>(Wz, Wrz_t + 1024ull*2048, 2048, 1024, 2048, 0, 0);
  transpose_k<<<dim3(32,16,1),  256, 0, stream>>>(Wh, Wh_t, 2048, 1024, 2048, 0, 0);
  cat2_kernel<<<8, 256, 0, stream>>>(br, bz, brzv);

  // compress: prop = pose @ W_compress + b_compress
  // 128x256 tile: 4 col-tiles x 8 rows x split-K=8 (id%8=ks), nt=100
  gemm_bf16<0,1><<<dim3(8,4,8), 512, 0, stream>>>(Abf, 25600, Wct, 25600,
      partial, 1024, 921600ull, nullptr, 900, 1024, 25600, 3200);
  reduce_compress<<<3600, 256, 0, stream>>>(partial, bc, prop, X);

  // ---- 6 recurrent iterations (last one: scores only) ----
  for (int it = 0; it < 6; it++) {
    attn_kernel<<<dim3(60,7), 256, 0, stream>>>(prop, u_row, u_col, crc, ba, scores);
    if (it == 5) break;
    // msg = prop @ W_edge + b_edge  (28 col-tiles of 256; MAP2: id%8=col%8)
    gemm_bf16<4,2><<<dim3(8,4,8), 512, 0, stream>>>(X + 1024, 2048, Wedge_t, 1024,
        (float*)msgb, 7168, 0, be, 900, 7168, 1024, 1024);
    merged_kernel<<<dim3(60,8), 256, 0, stream>>>(msgb, scores, X, Xh);
    // [r|z] partials = X @ [Wr|Wz]  (8 cols x 8 rows x ks=4 -> 256 blocks, nt=16)
    gemm_bf16<0,1><<<dim3(4,8,8), 512, 0, stream>>>(X, 2048, Wrz_t, 2048,
        partRZ, 2048, 1843200ull, nullptr, 900, 2048, 2048, 512);
    reduce_rz<<<7200, 256, 0, stream>>>(partRZ, brzv, prop, Zbuf, Xh);
    // h partials = Xh @ Wh  (4 cols x 8 rows x ks=8 -> 256 blocks, nt=8)
    gemm_bf16<0,0><<<dim3(4,8,8), 512, 0, stream>>>(Xh, 2048, Wh_t, 2048,
        partH, 1024, 921600ull, nullptr, 900, 1024, 2048, 256);
    reduce_h<<<3600, 256, 0, stream>>>(partH, bh, Zbuf, prop, X);
  }

  finalize_kernel<<<60, 256, 0, stream>>>(scores, out);
}

// Round 11
// 700.794 us; speedup vs baseline: 1.1006x; 1.1006x over previous
//
#include <hip/hip_runtime.h>
#include <hip/hip_bf16.h>

typedef unsigned short bf16_t;
typedef __bf16 bf16x8 __attribute__((ext_vector_type(8)));
typedef float f32x4 __attribute__((ext_vector_type(4)));
typedef unsigned short ushort8_t __attribute__((ext_vector_type(8)));

__device__ __forceinline__ unsigned short f2bf(float x){
  union { __hip_bfloat16 h; unsigned short u; } c;
  c.h = __float2bfloat16(x);
  return c.u;
}
__device__ __forceinline__ float bf2f(bf16_t u){
  union { unsigned short u; __hip_bfloat16 h; } c;
  c.u = u;
  return __bfloat162float(c.h);
}

// ---------------------------------------------------------------------------
// bf16 MFMA GEMM, 128x64 (MxN) tile, BK=32, 4 waves (2M x 2N), 64x32 out per
// wave, 256 threads. REG-STAGED double-buffered pipeline (the only staging
// engine that exceeded 1 TB/s effective BW in this session): per step each
// thread loads 3x16B global->VGPR (2 tiles ahead), ds_writes them 16B/lane
// conflict-free (1 tile ahead), ds_reads frags, 8 MFMA. One raw s_barrier +
// lgkmcnt(0) per step; NO global_load_lds, NO vmcnt drains (compiler tracks
// reg deps precisely).  24 KB LDS + <=128 VGPR -> 4 blocks/CU co-resident;
// grids sized 512-1024 blocks so occupancy (concurrency) is 2-4x previous.
// LDS image: row r at byte r*64, 16B-slot s holds k-group s^((r>>1)&3).
// MAP=0: blockIdx=(col,row,ks) -> id%8=col%8 (colTiles%8==0; B-sharers/XCD)
// MAP=1: blockIdx=(ks,col,row) -> id%8=ks   (split-K XCD streams; compress)
// ACT: 0 = f32 partial store at ks*csplit; 4 = bf16 store with bias.
// ---------------------------------------------------------------------------
template<int ACT, int MAP>
__global__ __launch_bounds__(256, 4)
void gemm_bf16(const bf16_t* __restrict__ A, int lda,
               const bf16_t* __restrict__ Bt, int ldb,
               float* __restrict__ C, int ldc, size_t csplit,
               const float* __restrict__ bias,
               int M, int N, int K, int Kchunk)
{
  __shared__ __align__(16) bf16_t As[2][128*32];   // 2 x 8 KB
  __shared__ __align__(16) bf16_t Bs[2][64*32];    // 2 x 4 KB
  const int tid = threadIdx.x;
  const int w = tid >> 6, lane = tid & 63;
  const int wm = w >> 1, wn = w & 1;
  const int lr = lane & 15, kq = lane >> 4;
  int bcol, brow, bks;
  if (MAP == 0) { bcol = blockIdx.x; brow = blockIdx.y; bks = blockIdx.z; }
  else          { bks = blockIdx.x;  bcol = blockIdx.y; brow = blockIdx.z; }
  const int gm0 = brow * 128, gn0 = bcol * 64;
  const int k0 = bks * Kchunk;
  const int nt = (min(k0 + Kchunk, K) - k0) >> 5;   // K-tiles (mult of 32)

  // staging: A image units u=tid (rows 0..63) and u=tid+256 (rows 64..127),
  // B image unit u=tid (rows 0..63). unit u -> row u>>2, slot u&3, source
  // k-group (u&3)^((row>>1)&3). 16B per unit; ds_write at byte u*16 ->
  // consecutive lanes hit consecutive banks (conflict-free).
  const int r0 = tid >> 2, s0 = tid & 3;
  const int kg0 = s0 ^ ((r0 >> 1) & 3);             // source k-group
  const int ar0 = min(gm0 + r0,      M-1);
  const int ar1 = min(gm0 + 64 + r0, M-1);
  const int br0 = min(gn0 + r0,      N-1);
  const bf16_t* pA0 = A  + (size_t)ar0*lda + k0 + kg0*8;
  const bf16_t* pA1 = A  + (size_t)ar1*lda + k0 + kg0*8;
  const bf16_t* pB0 = Bt + (size_t)br0*ldb + k0 + kg0*8;
  bf16_t* Al = &As[0][0] + tid*8;                   // byte tid*16
  bf16_t* Bl = &Bs[0][0] + tid*8;
  ushort8_t va0, va1, vb0;

#define LDT(t) do { \
    va0 = *(const ushort8_t*)(pA0 + (size_t)(t)*32); \
    va1 = *(const ushort8_t*)(pA1 + (size_t)(t)*32); \
    vb0 = *(const ushort8_t*)(pB0 + (size_t)(t)*32); \
  } while(0)
#define WRT(b) do { \
    *(ushort8_t*)(Al + (b)*4096)        = va0; \
    *(ushort8_t*)(Al + (b)*4096 + 2048) = va1; \
    *(ushort8_t*)(Bl + (b)*2048)        = vb0; } while(0)

  LDT(0); WRT(0);
  if (nt > 1) LDT(1);
  asm volatile("s_waitcnt lgkmcnt(0)" ::: "memory");
  __builtin_amdgcn_s_barrier();
  __builtin_amdgcn_sched_barrier(0);

  const int kqs = kq ^ ((lr >> 1) & 3);             // swizzled 16B slot
  f32x4 acc[4][2] = {};

  for (int t = 0; t < nt; ++t) {
    const int cb = t & 1;
    const bf16_t* Ab = &As[0][0] + cb*4096;
    const bf16_t* Bb = &Bs[0][0] + cb*2048;
    bf16x8 af[4], bfr[2];
#pragma unroll
    for (int mi = 0; mi < 4; mi++)
      af[mi] = *(const bf16x8*)((const char*)Ab + ((wm*64 + mi*16 + lr) << 6) + (kqs << 4));
#pragma unroll
    for (int ni = 0; ni < 2; ni++)
      bfr[ni] = *(const bf16x8*)((const char*)Bb + ((wn*32 + ni*16 + lr) << 6) + (kqs << 4));
    if (t + 1 < nt) WRT(cb ^ 1);     // tile t+1 (regs landed; auto vmcnt wait)
    if (t + 2 < nt) LDT(t + 2);      // issue loads for t+2
    __builtin_amdgcn_s_setprio(1);
#pragma unroll
    for (int mi = 0; mi < 4; mi++)
#pragma unroll
      for (int ni = 0; ni < 2; ni++)
        acc[mi][ni] = __builtin_amdgcn_mfma_f32_16x16x32_bf16(af[mi], bfr[ni], acc[mi][ni], 0, 0, 0);
    __builtin_amdgcn_s_setprio(0);
    asm volatile("s_waitcnt lgkmcnt(0)" ::: "memory");
    __builtin_amdgcn_s_barrier();
    __builtin_amdgcn_sched_barrier(0);
  }
#undef LDT
#undef WRT

  // epilogue: D row = kq*4 + i, col = lane&15 per 16x16 frag
#pragma unroll
  for (int mi = 0; mi < 4; mi++) {
#pragma unroll
    for (int ni = 0; ni < 2; ni++) {
      const int col = gn0 + wn*32 + ni*16 + lr;
      const float bv = (ACT == 4) ? bias[col] : 0.f;
#pragma unroll
      for (int i = 0; i < 4; i++) {
        const int row = gm0 + wm*64 + mi*16 + kq*4 + i;
        if (row < M) {
          const float v = acc[mi][ni][i] + bv;
          if (ACT == 4) ((bf16_t*)C)[(size_t)row*ldc + col] = f2bf(v);
          else C[(size_t)bks*csplit + (size_t)row*ldc + col] = v;
        }
      }
    }
  }
}

// sum split-K partials, add bias, write prop f32 + X right half bf16
__global__ void reduce_compress(const float* __restrict__ part, const float* __restrict__ bias,
                                float* __restrict__ prop, bf16_t* __restrict__ xr)
{
  const int idx = blockIdx.x*256 + threadIdx.x;   // < 921600
  const int m = idx >> 10, d = idx & 1023;
  float v = bias[d];
#pragma unroll
  for (int z = 0; z < 8; z++) v += part[(size_t)z*921600 + idx];
  prop[idx] = v;
  xr[(size_t)m*2048 + 1024 + d] = f2bf(v);
}

// RZ split-2 reduce: v = sigmoid(p0+p1+bias). col<1024: Xh_right = bf16(v*prop)
// (the r path); col>=1024: Zbuf = v (the z path).
__global__ void reduce_rz(const float* __restrict__ part, const float* __restrict__ bias,
                          const float* __restrict__ prop, float* __restrict__ Zbuf,
                          bf16_t* __restrict__ Xh)
{
  const int idx = blockIdx.x*256 + threadIdx.x;   // < 1843200
  const int m = idx >> 11, c = idx & 2047;
  float v = part[idx] + part[1843200 + idx] + bias[c];
  v = 1.f / (1.f + __expf(-v));
  if (c < 1024) Xh[(size_t)m*2048 + 1024 + c] = f2bf(v * prop[(size_t)m*1024 + c]);
  else          Zbuf[(size_t)m*1024 + (c - 1024)] = v;
}

// h split-4 reduce: h_hat = tanh(sum+bh); prop = (1-z)*prop + z*h_hat;
// also write X right half bf16.
__global__ void reduce_h(const float* __restrict__ part, const float* __restrict__ bias,
                         const float* __restrict__ Zbuf, float* __restrict__ prop,
                         bf16_t* __restrict__ X)
{
  const int idx = blockIdx.x*256 + threadIdx.x;   // < 921600
  const int m = idx >> 10, d = idx & 1023;
  float v = bias[d];
#pragma unroll
  for (int z = 0; z < 4; z++) v += part[(size_t)z*921600 + idx];
  v = tanhf(v);
  const float zz = Zbuf[idx];
  const float pn = (1.f - zz)*prop[idx] + zz*v;
  prop[idx] = pn;
  X[(size_t)m*2048 + 1024 + d] = f2bf(pn);
}

// u_row[e][h] = sum_d W_edge[e][h][d]*W_att[e][d]; u_col with W_att[e][1024+d]
__global__ void compute_u(const float* __restrict__ We, const float* __restrict__ Wa,
                          float* __restrict__ u_row, float* __restrict__ u_col)
{
  const int w = threadIdx.x >> 6, lane = threadIdx.x & 63;
  const int idx = blockIdx.x*4 + w;               // grid=1792 -> idx<7168
  const int e = idx >> 10, h = idx & 1023;
  const float* wep = We + ((size_t)e*1024 + h)*1024;
  const float* wr  = Wa + (size_t)e*2048;
  const float* wc  = wr + 1024;
  float ar = 0.f, ac = 0.f;
#pragma unroll
  for (int t = 0; t < 16; t++) {
    const float v = wep[lane + 64*t];
    ar += v*wr[lane + 64*t];
    ac += v*wc[lane + 64*t];
  }
  for (int off = 32; off; off >>= 1) { ar += __shfl_down(ar, off); ac += __shfl_down(ac, off); }
  if (lane == 0) { u_row[idx] = ar; u_col[idx] = ac; }
}

// crc[e] = b_edge[e].Wa_row[e], crc[7+e] = b_edge[e].Wa_col[e]
__global__ void crc_kernel(const float* __restrict__ be, const float* __restrict__ Wa,
                           float* __restrict__ crc)
{
  const int w = threadIdx.x >> 6, lane = threadIdx.x & 63;
  for (int idx = w; idx < 14; idx += 4) {
    const int e = idx >> 1, which = idx & 1;
    const float* bp = be + e*1024;
    const float* wp = Wa + (size_t)e*2048 + which*1024;
    float a = 0.f;
#pragma unroll
    for (int t = 0; t < 16; t++) a += bp[lane + 64*t]*wp[lane + 64*t];
    for (int off = 32; off; off >>= 1) a += __shfl_down(a, off);
    if (lane == 0) crc[which*7 + e] = a;
  }
}

// per (b,e): row[n]=prop[b,n,:].u_row[e]; col[n]=prop[b,n,:].u_col[e]
// scores[b,e,i,j] = sigmoid(row[i]+col[j]+b_att[e]+crc_row[e]+crc_col[e])
__global__ void attn_kernel(const float* __restrict__ prop, const float* __restrict__ u_row,
                            const float* __restrict__ u_col, const float* __restrict__ crc,
                            const float* __restrict__ b_att, float* __restrict__ scores)
{
  const int b = blockIdx.x, e = blockIdx.y;
  __shared__ float rowv[15], colv[15];
  const int w = threadIdx.x >> 6, lane = threadIdx.x & 63;
  const float* ur = u_row + (size_t)e*1024;
  const float* uc = u_col + (size_t)e*1024;
  for (int n = w; n < 15; n += 4) {
    const float* pr = prop + (size_t)(b*15 + n)*1024;
    float ar = 0.f, ac = 0.f;
#pragma unroll
    for (int t = 0; t < 16; t++) {
      const float pv = pr[lane + 64*t];
      ar += pv*ur[lane + 64*t];
      ac += pv*uc[lane + 64*t];
    }
    for (int off = 32; off; off >>= 1) { ar += __shfl_down(ar, off); ac += __shfl_down(ac, off); }
    if (lane == 0) { rowv[n] = ar; colv[n] = ac; }
  }
  __syncthreads();
  const float base = b_att[e] + crc[e] + crc[7 + e];
  for (int idx = threadIdx.x; idx < 225; idx += 256) {
    const int i = idx/15, j = idx - i*15;
    const float s = 1.f / (1.f + __expf(-(rowv[i] + colv[j] + base)));
    scores[((size_t)(b*7 + e)*15 + i)*15 + j] = s;
  }
}

// merged[b,i,d] = sum_e sum_j scores[b,e,i,j]*msg[b*15+j, e*1024+d]
// -> X left half AND Xh left half (bf16)
__global__ void merged_kernel(const bf16_t* __restrict__ msg, const float* __restrict__ scores,
                              bf16_t* __restrict__ X, bf16_t* __restrict__ Xh)
{
  const int b = blockIdx.x, c = blockIdx.y;   // c: 128-wide d-chunk, 8 chunks
  __shared__ float ms[15*7*128];              // [j][e][dl]
  __shared__ float sc[1575];                  // [e][i][j]
  for (int q = threadIdx.x; q < 3360; q += 256) {     // 4-wide bf16 loads
    const int idx = q*4;
    const int j = idx / 896;
    const int rem = idx - j*896;
    const int e = rem >> 7, dl = rem & 127;
    const ushort4 v = *(const ushort4*)(msg + (size_t)(b*15 + j)*7168 + e*1024 + c*128 + dl);
    ms[idx]   = bf2f(v.x);
    ms[idx+1] = bf2f(v.y);
    ms[idx+2] = bf2f(v.z);
    ms[idx+3] = bf2f(v.w);
  }
  for (int idx = threadIdx.x; idx < 1575; idx += 256)
    sc[idx] = scores[(size_t)b*1575 + idx];
  __syncthreads();
  for (int oi = threadIdx.x; oi < 1920; oi += 256) {
    const int i = oi >> 7, dl = oi & 127;
    float acc = 0.f;
#pragma unroll
    for (int e = 0; e < 7; e++)
#pragma unroll
      for (int j = 0; j < 15; j++)
        acc += sc[(e*15 + i)*15 + j] * ms[j*896 + e*128 + dl];
    const bf16_t o = f2bf(acc);
    X [(size_t)(b*15 + i)*2048 + c*128 + dl] = o;
    Xh[(size_t)(b*15 + i)*2048 + c*128 + dl] = o;
  }
}

// 64x64-tile transpose f32 -> bf16: out[c][r] = in[r][c]  (dims %64 == 0)
__global__ void transpose_k(const float* __restrict__ in, bf16_t* __restrict__ out,
                            int R, int C, int out_ld, size_t in_batch, size_t out_batch)
{
  __shared__ float t[64][65];
  in  += (size_t)blockIdx.z * in_batch;
  out += (size_t)blockIdx.z * out_batch;
  const int r0 = blockIdx.x*64, c0 = blockIdx.y*64;
  const int tc = threadIdx.x & 63, tr = threadIdx.x >> 6;
#pragma unroll
  for (int i = 0; i < 16; i++) {
    const int r = tr*16 + i;
    t[r][tc] = in[(size_t)(r0 + r)*C + c0 + tc];
  }
  __syncthreads();
#pragma unroll
  for (int i = 0; i < 16; i++) {
    const int rr = tr*16 + i;
    out[(size_t)(c0 + rr)*out_ld + r0 + tc] = f2bf(t[tc][rr]);
  }
}

__global__ void cast_f32_bf16(const float4* __restrict__ in, ushort4* __restrict__ out, int n4)
{
  int i = blockIdx.x*256 + threadIdx.x;
  const int stride = gridDim.x*256;
  for (; i < n4; i += stride) {
    const float4 v = in[i];
    out[i] = make_ushort4(f2bf(v.x), f2bf(v.y), f2bf(v.z), f2bf(v.w));
  }
}

__global__ void cat2_kernel(const float* __restrict__ a, const float* __restrict__ b,
                            float* __restrict__ o)
{
  const int i = blockIdx.x*256 + threadIdx.x;
  if (i < 1024) o[i] = a[i];
  else if (i < 2048) o[i] = b[i - 1024];
}

// final outputs from last-iteration scores
__global__ void finalize_kernel(const float* __restrict__ scores, float* __restrict__ out)
{
  const int b = blockIdx.x;   // 0..59
  __shared__ float sc[1575];
  __shared__ float act[105];
  __shared__ float asum[15];
  __shared__ float t2[7];
  for (int idx = threadIdx.x; idx < 1575; idx += 256)
    sc[idx] = scores[(size_t)b*1575 + idx];
  __syncthreads();
  for (int idx = threadIdx.x; idx < 105; idx += 256) {
    const int i = idx/7, e = idx - i*7;
    float a = 0.f;
#pragma unroll
    for (int j = 0; j < 15; j++)
      a += (1.f - sc[i*15 + j]) * sc[(e*15 + i)*15 + j];
    act[idx] = a;
    out[(size_t)b*105 + idx] = a;
  }
  for (int idx = threadIdx.x; idx < 225; idx += 256) {
    const int i = idx/15, j = idx - i*15;
    out[6660 + (size_t)b*225 + idx] = 1.f - sc[i*15 + j];
  }
  if (threadIdx.x < 15) {
    const int i = threadIdx.x;
    float s = 0.f;
#pragma unroll
    for (int j = 0; j < 15; j++) s += 1.f - sc[i*15 + j];
    asum[i] = s;
  }
  __syncthreads();
  if (threadIdx.x < 7) {
    const int e = threadIdx.x;
    float t = 0.f;
#pragma unroll
    for (int i = 0; i < 15; i++) t += act[i*7 + e]*asum[i];
    t2[e] = t;
  }
  __syncthreads();
  if (threadIdx.x == 0) {
    float mx = -1e30f;
    for (int e = 1; e < 7; e++) mx = fmaxf(mx, t2[e]);
    float s = 0.f, ex[6];
    for (int e = 1; e < 7; e++) { ex[e-1] = __expf(t2[e] - mx); s += ex[e-1]; }
    for (int e = 1; e < 7; e++) out[6300 + (size_t)b*6 + (e-1)] = ex[e-1]/s;
  }
}

extern "C" void kernel_launch(void* const* d_in, const int* in_sizes, int n_in,
                              void* d_out, int out_size, void* d_ws, size_t ws_size,
                              hipStream_t stream)
{
  const float* pose = (const float*)d_in[0];
  const float* Wc   = (const float*)d_in[1];
  const float* bc   = (const float*)d_in[2];
  const float* We   = (const float*)d_in[3];
  const float* be   = (const float*)d_in[4];
  const float* Wa   = (const float*)d_in[5];
  const float* ba   = (const float*)d_in[6];
  const float* Wr   = (const float*)d_in[7];
  const float* br   = (const float*)d_in[8];
  const float* Wz   = (const float*)d_in[9];
  const float* bz   = (const float*)d_in[10];
  const float* Wh   = (const float*)d_in[11];
  const float* bh   = (const float*)d_in[12];
  float* out = (float*)d_out;

  // ---- workspace carving ----
  char* p = (char*)d_ws;
  auto alloc = [&](size_t b) { char* r = p; p += (b + 255) & ~(size_t)255; return r; };
  bf16_t* Wedge_t = (bf16_t*)alloc(7168ull*1024*2);   // [e*1024+d][h]
  bf16_t* Wrz_t   = (bf16_t*)alloc(2048ull*2048*2);   // [n][k]
  bf16_t* Wh_t    = (bf16_t*)alloc(1024ull*2048*2);   // [n][k]
  bf16_t* X       = (bf16_t*)alloc(900ull*2048*2);    // [merged | prop] bf16
  float*  prop    = (float*) alloc(900ull*1024*4);    // f32 master state
  float*  scores  = (float*) alloc(60ull*7*15*15*4);
  float*  u_row   = (float*) alloc(7168*4);
  float*  u_col   = (float*) alloc(7168*4);
  float*  crc     = (float*) alloc(64);
  float*  brzv    = (float*) alloc(2048*4);
  // phase-union region:
  // phase1 (compress): Abf(46.08) + Wct(52.43) + partial(29.49) = 128 MB
  // phase2 (iters): msgb 12.9 | Zbuf 3.69 | Xh 3.69 | partRZ 29.5 | partH 14.7
  char* r1 = alloc(128000000ull);
  bf16_t* Abf     = (bf16_t*)r1;
  bf16_t* Wct     = (bf16_t*)(r1 + 46080000ull);
  float*  partial = (float*) (r1 + 46080000ull + 52428800ull);
  bf16_t* msgb    = (bf16_t*)r1;
  float*  Zbuf    = (float*) (r1 + 12902400ull);
  bf16_t* Xh      = (bf16_t*)(r1 + 16588800ull);
  float*  partRZ  = (float*) (r1 + 20275200ull);      // 2 x 900 x 2048 f32
  float*  partH   = (float*) (r1 + 49766400ull);      // 4 x 900 x 1024 f32

  // ---- precompute ----
  compute_u<<<1792, 256, 0, stream>>>(We, Wa, u_row, u_col);
  crc_kernel<<<1, 256, 0, stream>>>(be, Wa, crc);
  cast_f32_bf16<<<2048, 256, 0, stream>>>((const float4*)pose, (ushort4*)Abf, 23040000/4);
  transpose_k<<<dim3(400,16,1), 256, 0, stream>>>(Wc, Wct, 25600, 1024, 25600, 0, 0);
  transpose_k<<<dim3(16,16,7),  256, 0, stream>>>(We, Wedge_t, 1024, 1024, 1024,
                                                  1024ull*1024, 1024ull*1024);
  transpose_k<<<dim3(32,16,1),  256, 0, stream>>>(Wr, Wrz_t, 2048, 1024, 2048, 0, 0);
  transpose_k<<<dim3(32,16,1),  256, 0, stream>>>(Wz, Wrz_t + 1024ull*2048, 2048, 1024, 2048, 0, 0);
  transpose_k<<<dim3(32,16,1),  256, 0, stream>>>(Wh, Wh_t, 2048, 1024, 2048, 0, 0);
  cat2_kernel<<<8, 256, 0, stream>>>(br, bz, brzv);

  // compress: prop = pose @ W_compress + b_compress
  // 128x64 tiles: 16 cols x 8 rows x ks=8 (MAP1, id%8=ks) = 1024 blocks, nt=100
  gemm_bf16<0,1><<<dim3(8,16,8), 256, 0, stream>>>(Abf, 25600, Wct, 25600,
      partial, 1024, 921600ull, nullptr, 900, 1024, 25600, 3200);
  reduce_compress<<<3600, 256, 0, stream>>>(partial, bc, prop, X);

  // ---- 6 recurrent iterations (last one: scores only) ----
  for (int it = 0; it < 6; it++) {
    attn_kernel<<<dim3(60,7), 256, 0, stream>>>(prop, u_row, u_col, crc, ba, scores);
    if (it == 5) break;
    // msg = prop @ W_edge + b_edge  (112 col-tiles x 8 rows = 896 blocks,
    // id%8 = col%8, nt=32)
    gemm_bf16<4,0><<<dim3(112,8,1), 256, 0, stream>>>(X + 1024, 2048, Wedge_t, 1024,
        (float*)msgb, 7168, 0, be, 900, 7168, 1024, 1024);
    merged_kernel<<<dim3(60,8), 256, 0, stream>>>(msgb, scores, X, Xh);
    // [r|z] partials = X @ [Wr|Wz]  (32 cols x 8 rows x ks=2 = 512, nt=32)
    gemm_bf16<0,0><<<dim3(32,8,2), 256, 0, stream>>>(X, 2048, Wrz_t, 2048,
        partRZ, 2048, 1843200ull, nullptr, 900, 2048, 2048, 1024);
    reduce_rz<<<7200, 256, 0, stream>>>(partRZ, brzv, prop, Zbuf, Xh);
    // h partials = Xh @ Wh  (16 cols x 8 rows x ks=4 = 512 blocks, nt=16)
    gemm_bf16<0,0><<<dim3(16,8,4), 256, 0, stream>>>(Xh, 2048, Wh_t, 2048,
        partH, 1024, 921600ull, nullptr, 900, 1024, 2048, 512);
    reduce_h<<<3600, 256, 0, stream>>>(partH, bh, Zbuf, prop, X);
  }

  finalize_kernel<<<60, 256, 0, stream>>>(scores, out);
}

// Round 12
// 689.937 us; speedup vs baseline: 1.1179x; 1.0157x over previous
//
#include <hip/hip_runtime.h>
#include <hip/hip_bf16.h>

typedef unsigned short bf16_t;
typedef __bf16 bf16x8 __attribute__((ext_vector_type(8)));
typedef float f32x4 __attribute__((ext_vector_type(4)));
typedef unsigned short ushort8_t __attribute__((ext_vector_type(8)));

__device__ __forceinline__ unsigned short f2bf(float x){
  union { __hip_bfloat16 h; unsigned short u; } c;
  c.h = __float2bfloat16(x);
  return c.u;
}
__device__ __forceinline__ float bf2f(bf16_t u){
  union { unsigned short u; __hip_bfloat16 h; } c;
  c.u = u;
  return __bfloat162float(c.h);
}

// ---------------------------------------------------------------------------
// bf16 MFMA GEMM, 128x64 (MxN) tile, BK=64, 4 waves (2M x 2N), 256 threads.
// Reg-staged double-buffered pipeline with 2x the memory-level parallelism of
// the BK=32 version: per step each thread holds 6x16B loads in flight
// (A rows r,r+32,r+64,r+96; B rows r,r+32), ds_writes them lane-linear
// (conflict-free), then 12 ds_reads + 16 MFMA per step. HALF the barrier
// rounds of BK=32. One raw s_barrier + lgkmcnt(0) per step; no vmcnt drains.
// LDS image: row r at byte r*128 (8 slots of 16B); slot s holds k-group
// s^(r&7) -> frag reads are 2-way max, writes conflict-free.
// 48 KB LDS, __launch_bounds__(256,3) -> 3 blocks/CU.
// MAP=0: blockIdx=(col,row,ks) -> id%8=col%8 (colTiles%8==0)
// MAP=1: blockIdx=(ks,col,row) -> id%8=ks   (split-K XCD streams)
// ACT: 0 = f32 partial store at ks*csplit; 4 = bf16 store with bias.
// Kchunk must be a multiple of 64.
// ---------------------------------------------------------------------------
template<int ACT, int MAP>
__global__ __launch_bounds__(256, 3)
void gemm_bf16(const bf16_t* __restrict__ A, int lda,
               const bf16_t* __restrict__ Bt, int ldb,
               float* __restrict__ C, int ldc, size_t csplit,
               const float* __restrict__ bias,
               int M, int N, int K, int Kchunk)
{
  __shared__ __align__(16) bf16_t As[2][128*64];   // 2 x 16 KB
  __shared__ __align__(16) bf16_t Bs[2][64*64];    // 2 x 8 KB
  const int tid = threadIdx.x;
  const int w = tid >> 6, lane = tid & 63;
  const int wm = w >> 1, wn = w & 1;
  const int lr = lane & 15, kq = lane >> 4;
  int bcol, brow, bks;
  if (MAP == 0) { bcol = blockIdx.x; brow = blockIdx.y; bks = blockIdx.z; }
  else          { bks = blockIdx.x;  bcol = blockIdx.y; brow = blockIdx.z; }
  const int gm0 = brow * 128, gn0 = bcol * 64;
  const int k0 = bks * Kchunk;
  const int nt = (min(k0 + Kchunk, K) - k0) >> 6;   // K-slabs of 64

  // staging: thread t sources k-group kg0 = (t&7)^((t>>3)&7), 8 bf16 wide.
  // A units: rows r0+32j (j=0..3); B units: rows r0+32j (j=0..1).
  const int r0 = tid >> 3;
  const int kg0 = (tid & 7) ^ (r0 & 7);
  const int ka = kg0 * 8;
  const int ar0 = min(gm0 + r0,      M-1);
  const int ar1 = min(gm0 + r0 + 32, M-1);
  const int ar2 = min(gm0 + r0 + 64, M-1);
  const int ar3 = min(gm0 + r0 + 96, M-1);
  const int br0 = min(gn0 + r0,      N-1);
  const int br1 = min(gn0 + r0 + 32, N-1);
  const bf16_t* pA0 = A  + (size_t)ar0*lda + k0 + ka;
  const bf16_t* pA1 = A  + (size_t)ar1*lda + k0 + ka;
  const bf16_t* pA2 = A  + (size_t)ar2*lda + k0 + ka;
  const bf16_t* pA3 = A  + (size_t)ar3*lda + k0 + ka;
  const bf16_t* pB0 = Bt + (size_t)br0*ldb + k0 + ka;
  const bf16_t* pB1 = Bt + (size_t)br1*ldb + k0 + ka;
  bf16_t* Al = &As[0][0] + tid*8;    // unit v=tid+256j at elem tid*8+j*2048
  bf16_t* Bl = &Bs[0][0] + tid*8;
  ushort8_t va0, va1, va2, va3, vb0, vb1;

#define LDT(t) do { \
    va0 = *(const ushort8_t*)(pA0 + (size_t)(t)*64); \
    va1 = *(const ushort8_t*)(pA1 + (size_t)(t)*64); \
    va2 = *(const ushort8_t*)(pA2 + (size_t)(t)*64); \
    va3 = *(const ushort8_t*)(pA3 + (size_t)(t)*64); \
    vb0 = *(const ushort8_t*)(pB0 + (size_t)(t)*64); \
    vb1 = *(const ushort8_t*)(pB1 + (size_t)(t)*64); \
  } while(0)
#define WRT(b) do { \
    *(ushort8_t*)(Al + (b)*8192)        = va0; \
    *(ushort8_t*)(Al + (b)*8192 + 2048) = va1; \
    *(ushort8_t*)(Al + (b)*8192 + 4096) = va2; \
    *(ushort8_t*)(Al + (b)*8192 + 6144) = va3; \
    *(ushort8_t*)(Bl + (b)*4096)        = vb0; \
    *(ushort8_t*)(Bl + (b)*4096 + 2048) = vb1; } while(0)

  LDT(0); WRT(0);
  if (nt > 1) LDT(1);
  asm volatile("s_waitcnt lgkmcnt(0)" ::: "memory");
  __builtin_amdgcn_s_barrier();
  __builtin_amdgcn_sched_barrier(0);

  // frag reads: row&7 == lr&7 for all frags (offsets are multiples of 8/16)
  const int ph = lr & 7;                     // XOR term for phys slot
  f32x4 acc[4][2] = {};

  for (int t = 0; t < nt; ++t) {
    const int cb = t & 1;
    const bf16_t* Ab = &As[0][0] + cb*8192;
    const bf16_t* Bb = &Bs[0][0] + cb*4096;
    bf16x8 af[2][4], bfr[2][2];
#pragma unroll
    for (int ks = 0; ks < 2; ks++) {
      const int phys = (ks*4 + kq) ^ ph;     // physical 16B slot
#pragma unroll
      for (int mi = 0; mi < 4; mi++)
        af[ks][mi] = *(const bf16x8*)(Ab + (wm*64 + mi*16 + lr)*64 + phys*8);
#pragma unroll
      for (int ni = 0; ni < 2; ni++)
        bfr[ks][ni] = *(const bf16x8*)(Bb + (wn*32 + ni*16 + lr)*64 + phys*8);
    }
    if (t + 1 < nt) WRT(cb ^ 1);     // tile t+1 (regs landed; auto vmcnt wait)
    if (t + 2 < nt) LDT(t + 2);      // issue loads for t+2
    __builtin_amdgcn_s_setprio(1);
#pragma unroll
    for (int ks = 0; ks < 2; ks++)
#pragma unroll
      for (int mi = 0; mi < 4; mi++)
#pragma unroll
        for (int ni = 0; ni < 2; ni++)
          acc[mi][ni] = __builtin_amdgcn_mfma_f32_16x16x32_bf16(af[ks][mi], bfr[ks][ni], acc[mi][ni], 0, 0, 0);
    __builtin_amdgcn_s_setprio(0);
    asm volatile("s_waitcnt lgkmcnt(0)" ::: "memory");
    __builtin_amdgcn_s_barrier();
    __builtin_amdgcn_sched_barrier(0);
  }
#undef LDT
#undef WRT

  // epilogue: D row = kq*4 + i, col = lane&15 per 16x16 frag
#pragma unroll
  for (int mi = 0; mi < 4; mi++) {
#pragma unroll
    for (int ni = 0; ni < 2; ni++) {
      const int col = gn0 + wn*32 + ni*16 + lr;
      const float bv = (ACT == 4) ? bias[col] : 0.f;
#pragma unroll
      for (int i = 0; i < 4; i++) {
        const int row = gm0 + wm*64 + mi*16 + kq*4 + i;
        if (row < M) {
          const float v = acc[mi][ni][i] + bv;
          if (ACT == 4) ((bf16_t*)C)[(size_t)row*ldc + col] = f2bf(v);
          else C[(size_t)bks*csplit + (size_t)row*ldc + col] = v;
        }
      }
    }
  }
}

// sum split-K partials, add bias, write prop f32 + X right half bf16
__global__ void reduce_compress(const float* __restrict__ part, const float* __restrict__ bias,
                                float* __restrict__ prop, bf16_t* __restrict__ xr)
{
  const int idx = blockIdx.x*256 + threadIdx.x;   // < 921600
  const int m = idx >> 10, d = idx & 1023;
  float v = bias[d];
#pragma unroll
  for (int z = 0; z < 8; z++) v += part[(size_t)z*921600 + idx];
  prop[idx] = v;
  xr[(size_t)m*2048 + 1024 + d] = f2bf(v);
}

// RZ split-2 reduce: v = sigmoid(p0+p1+bias). col<1024: Xh_right = bf16(v*prop)
// (the r path); col>=1024: Zbuf = v (the z path).
__global__ void reduce_rz(const float* __restrict__ part, const float* __restrict__ bias,
                          const float* __restrict__ prop, float* __restrict__ Zbuf,
                          bf16_t* __restrict__ Xh)
{
  const int idx = blockIdx.x*256 + threadIdx.x;   // < 1843200
  const int m = idx >> 11, c = idx & 2047;
  float v = part[idx] + part[1843200 + idx] + bias[c];
  v = 1.f / (1.f + __expf(-v));
  if (c < 1024) Xh[(size_t)m*2048 + 1024 + c] = f2bf(v * prop[(size_t)m*1024 + c]);
  else          Zbuf[(size_t)m*1024 + (c - 1024)] = v;
}

// h split-4 reduce: h_hat = tanh(sum+bh); prop = (1-z)*prop + z*h_hat;
// also write X right half bf16.
__global__ void reduce_h(const float* __restrict__ part, const float* __restrict__ bias,
                         const float* __restrict__ Zbuf, float* __restrict__ prop,
                         bf16_t* __restrict__ X)
{
  const int idx = blockIdx.x*256 + threadIdx.x;   // < 921600
  const int m = idx >> 10, d = idx & 1023;
  float v = bias[d];
#pragma unroll
  for (int z = 0; z < 4; z++) v += part[(size_t)z*921600 + idx];
  v = tanhf(v);
  const float zz = Zbuf[idx];
  const float pn = (1.f - zz)*prop[idx] + zz*v;
  prop[idx] = pn;
  X[(size_t)m*2048 + 1024 + d] = f2bf(pn);
}

// u_row[e][h] = sum_d W_edge[e][h][d]*W_att[e][d]; u_col with W_att[e][1024+d]
__global__ void compute_u(const float* __restrict__ We, const float* __restrict__ Wa,
                          float* __restrict__ u_row, float* __restrict__ u_col)
{
  const int w = threadIdx.x >> 6, lane = threadIdx.x & 63;
  const int idx = blockIdx.x*4 + w;               // grid=1792 -> idx<7168
  const int e = idx >> 10, h = idx & 1023;
  const float* wep = We + ((size_t)e*1024 + h)*1024;
  const float* wr  = Wa + (size_t)e*2048;
  const float* wc  = wr + 1024;
  float ar = 0.f, ac = 0.f;
#pragma unroll
  for (int t = 0; t < 16; t++) {
    const float v = wep[lane + 64*t];
    ar += v*wr[lane + 64*t];
    ac += v*wc[lane + 64*t];
  }
  for (int off = 32; off; off >>= 1) { ar += __shfl_down(ar, off); ac += __shfl_down(ac, off); }
  if (lane == 0) { u_row[idx] = ar; u_col[idx] = ac; }
}

// crc[e] = b_edge[e].Wa_row[e], crc[7+e] = b_edge[e].Wa_col[e]
__global__ void crc_kernel(const float* __restrict__ be, const float* __restrict__ Wa,
                           float* __restrict__ crc)
{
  const int w = threadIdx.x >> 6, lane = threadIdx.x & 63;
  for (int idx = w; idx < 14; idx += 4) {
    const int e = idx >> 1, which = idx & 1;
    const float* bp = be + e*1024;
    const float* wp = Wa + (size_t)e*2048 + which*1024;
    float a = 0.f;
#pragma unroll
    for (int t = 0; t < 16; t++) a += bp[lane + 64*t]*wp[lane + 64*t];
    for (int off = 32; off; off >>= 1) a += __shfl_down(a, off);
    if (lane == 0) crc[which*7 + e] = a;
  }
}

// per (b,e): row[n]=prop[b,n,:].u_row[e]; col[n]=prop[b,n,:].u_col[e]
// scores[b,e,i,j] = sigmoid(row[i]+col[j]+b_att[e]+crc_row[e]+crc_col[e])
__global__ void attn_kernel(const float* __restrict__ prop, const float* __restrict__ u_row,
                            const float* __restrict__ u_col, const float* __restrict__ crc,
                            const float* __restrict__ b_att, float* __restrict__ scores)
{
  const int b = blockIdx.x, e = blockIdx.y;
  __shared__ float rowv[15], colv[15];
  const int w = threadIdx.x >> 6, lane = threadIdx.x & 63;
  const float* ur = u_row + (size_t)e*1024;
  const float* uc = u_col + (size_t)e*1024;
  for (int n = w; n < 15; n += 4) {
    const float* pr = prop + (size_t)(b*15 + n)*1024;
    float ar = 0.f, ac = 0.f;
#pragma unroll
    for (int t = 0; t < 16; t++) {
      const float pv = pr[lane + 64*t];
      ar += pv*ur[lane + 64*t];
      ac += pv*uc[lane + 64*t];
    }
    for (int off = 32; off; off >>= 1) { ar += __shfl_down(ar, off); ac += __shfl_down(ac, off); }
    if (lane == 0) { rowv[n] = ar; colv[n] = ac; }
  }
  __syncthreads();
  const float base = b_att[e] + crc[e] + crc[7 + e];
  for (int idx = threadIdx.x; idx < 225; idx += 256) {
    const int i = idx/15, j = idx - i*15;
    const float s = 1.f / (1.f + __expf(-(rowv[i] + colv[j] + base)));
    scores[((size_t)(b*7 + e)*15 + i)*15 + j] = s;
  }
}

// merged[b,i,d] = sum_e sum_j scores[b,e,i,j]*msg[b*15+j, e*1024+d]
// -> X left half AND Xh left half (bf16)
__global__ void merged_kernel(const bf16_t* __restrict__ msg, const float* __restrict__ scores,
                              bf16_t* __restrict__ X, bf16_t* __restrict__ Xh)
{
  const int b = blockIdx.x, c = blockIdx.y;   // c: 128-wide d-chunk, 8 chunks
  __shared__ float ms[15*7*128];              // [j][e][dl]
  __shared__ float sc[1575];                  // [e][i][j]
  for (int q = threadIdx.x; q < 3360; q += 256) {     // 4-wide bf16 loads
    const int idx = q*4;
    const int j = idx / 896;
    const int rem = idx - j*896;
    const int e = rem >> 7, dl = rem & 127;
    const ushort4 v = *(const ushort4*)(msg + (size_t)(b*15 + j)*7168 + e*1024 + c*128 + dl);
    ms[idx]   = bf2f(v.x);
    ms[idx+1] = bf2f(v.y);
    ms[idx+2] = bf2f(v.z);
    ms[idx+3] = bf2f(v.w);
  }
  for (int idx = threadIdx.x; idx < 1575; idx += 256)
    sc[idx] = scores[(size_t)b*1575 + idx];
  __syncthreads();
  for (int oi = threadIdx.x; oi < 1920; oi += 256) {
    const int i = oi >> 7, dl = oi & 127;
    float acc = 0.f;
#pragma unroll
    for (int e = 0; e < 7; e++)
#pragma unroll
      for (int j = 0; j < 15; j++)
        acc += sc[(e*15 + i)*15 + j] * ms[j*896 + e*128 + dl];
    const bf16_t o = f2bf(acc);
    X [(size_t)(b*15 + i)*2048 + c*128 + dl] = o;
    Xh[(size_t)(b*15 + i)*2048 + c*128 + dl] = o;
  }
}

// 64x64-tile transpose f32 -> bf16: out[c][r] = in[r][c]  (dims %64 == 0)
__global__ void transpose_k(const float* __restrict__ in, bf16_t* __restrict__ out,
                            int R, int C, int out_ld, size_t in_batch, size_t out_batch)
{
  __shared__ float t[64][65];
  in  += (size_t)blockIdx.z * in_batch;
  out += (size_t)blockIdx.z * out_batch;
  const int r0 = blockIdx.x*64, c0 = blockIdx.y*64;
  const int tc = threadIdx.x & 63, tr = threadIdx.x >> 6;
#pragma unroll
  for (int i = 0; i < 16; i++) {
    const int r = tr*16 + i;
    t[r][tc] = in[(size_t)(r0 + r)*C + c0 + tc];
  }
  __syncthreads();
#pragma unroll
  for (int i = 0; i < 16; i++) {
    const int rr = tr*16 + i;
    out[(size_t)(c0 + rr)*out_ld + r0 + tc] = f2bf(t[tc][rr]);
  }
}

__global__ void cast_f32_bf16(const float4* __restrict__ in, ushort4* __restrict__ out, int n4)
{
  int i = blockIdx.x*256 + threadIdx.x;
  const int stride = gridDim.x*256;
  for (; i < n4; i += stride) {
    const float4 v = in[i];
    out[i] = make_ushort4(f2bf(v.x), f2bf(v.y), f2bf(v.z), f2bf(v.w));
  }
}

__global__ void cat2_kernel(const float* __restrict__ a, const float* __restrict__ b,
                            float* __restrict__ o)
{
  const int i = blockIdx.x*256 + threadIdx.x;
  if (i < 1024) o[i] = a[i];
  else if (i < 2048) o[i] = b[i - 1024];
}

// final outputs from last-iteration scores
__global__ void finalize_kernel(const float* __restrict__ scores, float* __restrict__ out)
{
  const int b = blockIdx.x;   // 0..59
  __shared__ float sc[1575];
  __shared__ float act[105];
  __shared__ float asum[15];
  __shared__ float t2[7];
  for (int idx = threadIdx.x; idx < 1575; idx += 256)
    sc[idx] = scores[(size_t)b*1575 + idx];
  __syncthreads();
  for (int idx = threadIdx.x; idx < 105; idx += 256) {
    const int i = idx/7, e = idx - i*7;
    float a = 0.f;
#pragma unroll
    for (int j = 0; j < 15; j++)
      a += (1.f - sc[i*15 + j]) * sc[(e*15 + i)*15 + j];
    act[idx] = a;
    out[(size_t)b*105 + idx] = a;
  }
  for (int idx = threadIdx.x; idx < 225; idx += 256) {
    const int i = idx/15, j = idx - i*15;
    out[6660 + (size_t)b*225 + idx] = 1.f - sc[i*15 + j];
  }
  if (threadIdx.x < 15) {
    const int i = threadIdx.x;
    float s = 0.f;
#pragma unroll
    for (int j = 0; j < 15; j++) s += 1.f - sc[i*15 + j];
    asum[i] = s;
  }
  __syncthreads();
  if (threadIdx.x < 7) {
    const int e = threadIdx.x;
    float t = 0.f;
#pragma unroll
    for (int i = 0; i < 15; i++) t += act[i*7 + e]*asum[i];
    t2[e] = t;
  }
  __syncthreads();
  if (threadIdx.x == 0) {
    float mx = -1e30f;
    for (int e = 1; e < 7; e++) mx = fmaxf(mx, t2[e]);
    float s = 0.f, ex[6];
    for (int e = 1; e < 7; e++) { ex[e-1] = __expf(t2[e] - mx); s += ex[e-1]; }
    for (int e = 1; e < 7; e++) out[6300 + (size_t)b*6 + (e-1)] = ex[e-1]/s;
  }
}

extern "C" void kernel_launch(void* const* d_in, const int* in_sizes, int n_in,
                              void* d_out, int out_size, void* d_ws, size_t ws_size,
                              hipStream_t stream)
{
  const float* pose = (const float*)d_in[0];
  const float* Wc   = (const float*)d_in[1];
  const float* bc   = (const float*)d_in[2];
  const float* We   = (const float*)d_in[3];
  const float* be   = (const float*)d_in[4];
  const float* Wa   = (const float*)d_in[5];
  const float* ba   = (const float*)d_in[6];
  const float* Wr   = (const float*)d_in[7];
  const float* br   = (const float*)d_in[8];
  const float* Wz   = (const float*)d_in[9];
  const float* bz   = (const float*)d_in[10];
  const float* Wh   = (const float*)d_in[11];
  const float* bh   = (const float*)d_in[12];
  float* out = (float*)d_out;

  // ---- workspace carving ----
  char* p = (char*)d_ws;
  auto alloc = [&](size_t b) { char* r = p; p += (b + 255) & ~(size_t)255; return r; };
  bf16_t* Wedge_t = (bf16_t*)alloc(7168ull*1024*2);   // [e*1024+d][h]
  bf16_t* Wrz_t   = (bf16_t*)alloc(2048ull*2048*2);   // [n][k]
  bf16_t* Wh_t    = (bf16_t*)alloc(1024ull*2048*2);   // [n][k]
  bf16_t* X       = (bf16_t*)alloc(900ull*2048*2);    // [merged | prop] bf16
  float*  prop    = (float*) alloc(900ull*1024*4);    // f32 master state
  float*  scores  = (float*) alloc(60ull*7*15*15*4);
  float*  u_row   = (float*) alloc(7168*4);
  float*  u_col   = (float*) alloc(7168*4);
  float*  crc     = (float*) alloc(64);
  float*  brzv    = (float*) alloc(2048*4);
  // phase-union region:
  // phase1 (compress): Abf(46.08) + Wct(52.43) + partial(29.49) = 128 MB
  // phase2 (iters): msgb 12.9 | Zbuf 3.69 | Xh 3.69 | partRZ 29.5 | partH 14.7
  char* r1 = alloc(128000000ull);
  bf16_t* Abf     = (bf16_t*)r1;
  bf16_t* Wct     = (bf16_t*)(r1 + 46080000ull);
  float*  partial = (float*) (r1 + 46080000ull + 52428800ull);
  bf16_t* msgb    = (bf16_t*)r1;
  float*  Zbuf    = (float*) (r1 + 12902400ull);
  bf16_t* Xh      = (bf16_t*)(r1 + 16588800ull);
  float*  partRZ  = (float*) (r1 + 20275200ull);      // 2 x 900 x 2048 f32
  float*  partH   = (float*) (r1 + 49766400ull);      // 4 x 900 x 1024 f32

  // ---- precompute ----
  compute_u<<<1792, 256, 0, stream>>>(We, Wa, u_row, u_col);
  crc_kernel<<<1, 256, 0, stream>>>(be, Wa, crc);
  cast_f32_bf16<<<2048, 256, 0, stream>>>((const float4*)pose, (ushort4*)Abf, 23040000/4);
  transpose_k<<<dim3(400,16,1), 256, 0, stream>>>(Wc, Wct, 25600, 1024, 25600, 0, 0);
  transpose_k<<<dim3(16,16,7),  256, 0, stream>>>(We, Wedge_t, 1024, 1024, 1024,
                                                  1024ull*1024, 1024ull*1024);
  transpose_k<<<dim3(32,16,1),  256, 0, stream>>>(Wr, Wrz_t, 2048, 1024, 2048, 0, 0);
  transpose_k<<<dim3(32,16,1),  256, 0, stream>>>(Wz, Wrz_t + 1024ull*2048, 2048, 1024, 2048, 0, 0);
  transpose_k<<<dim3(32,16,1),  256, 0, stream>>>(Wh, Wh_t, 2048, 1024, 2048, 0, 0);
  cat2_kernel<<<8, 256, 0, stream>>>(br, bz, brzv);

  // compress: prop = pose @ W_compress + b_compress
  // 128x64 tiles: 16 cols x 8 rows x ks=8 (MAP1, id%8=ks), nt=50 (BK=64)
  gemm_bf16<0,1><<<dim3(8,16,8), 256, 0, stream>>>(Abf, 25600, Wct, 25600,
      partial, 1024, 921600ull, nullptr, 900, 1024, 25600, 3200);
  reduce_compress<<<3600, 256, 0, stream>>>(partial, bc, prop, X);

  // ---- 6 recurrent iterations (last one: scores only) ----
  for (int it = 0; it < 6; it++) {
    attn_kernel<<<dim3(60,7), 256, 0, stream>>>(prop, u_row, u_col, crc, ba, scores);
    if (it == 5) break;
    // msg = prop @ W_edge + b_edge  (112 col-tiles x 8 rows = 896 blocks,
    // id%8 = col%8, nt=16)
    gemm_bf16<4,0><<<dim3(112,8,1), 256, 0, stream>>>(X + 1024, 2048, Wedge_t, 1024,
        (float*)msgb, 7168, 0, be, 900, 7168, 1024, 1024);
    merged_kernel<<<dim3(60,8), 256, 0, stream>>>(msgb, scores, X, Xh);
    // [r|z] partials = X @ [Wr|Wz]  (32 cols x 8 rows x ks=2 = 512, nt=16)
    gemm_bf16<0,0><<<dim3(32,8,2), 256, 0, stream>>>(X, 2048, Wrz_t, 2048,
        partRZ, 2048, 1843200ull, nullptr, 900, 2048, 2048, 1024);
    reduce_rz<<<7200, 256, 0, stream>>>(partRZ, brzv, prop, Zbuf, Xh);
    // h partials = Xh @ Wh  (16 cols x 8 rows x ks=4 = 512 blocks, nt=8)
    gemm_bf16<0,0><<<dim3(16,8,4), 256, 0, stream>>>(Xh, 2048, Wh_t, 2048,
        partH, 1024, 921600ull, nullptr, 900, 1024, 2048, 512);
    reduce_h<<<3600, 256, 0, stream>>>(partH, bh, Zbuf, prop, X);
  }

  finalize_kernel<<<60, 256, 0, stream>>>(scores, out);
}

// Round 13
// 641.176 us; speedup vs baseline: 1.2029x; 1.0760x over previous
//
#include <hip/hip_runtime.h>
#include <hip/hip_bf16.h>

typedef unsigned short bf16_t;
typedef __bf16 bf16x8 __attribute__((ext_vector_type(8)));
typedef float f32x4 __attribute__((ext_vector_type(4)));
typedef unsigned short ushort8_t __attribute__((ext_vector_type(8)));

__device__ __forceinline__ unsigned short f2bf(float x){
  union { __hip_bfloat16 h; unsigned short u; } c;
  c.h = __float2bfloat16(x);
  return c.u;
}
__device__ __forceinline__ float bf2f(bf16_t u){
  union { unsigned short u; __hip_bfloat16 h; } c;
  c.u = u;
  return __bfloat162float(c.h);
}

// ---------------------------------------------------------------------------
// bf16 MFMA GEMM, 128x128 tile, BK=64, 4 waves (2x2), 64x64 out per wave
// (4x4 frags), 256 threads. Reg-staged double-buffered pipeline.
// WHY this shape: R12 analysis showed these GEMMs are LDS-ISSUE-bound
// (12 ds_read + 6 ds_write b128 per thread-step ~ 864 of 1128 cyc/block-step).
// 64x64 per-wave raises MFMA:ds_read to 2:1 (16 reads + 8 writes -> 32 MFMA
// per thread-step), halving per-MFMA LDS cost; block count also halves.
// Staging: 4 A units + 4 B units per thread (16B each, lane-linear ds_write,
// conflict-free); LDS image row r at 128B, slot s holds k-group s^(r&7)
// (frag reads 2-way max). One raw s_barrier + lgkmcnt(0) per step; no
// vmcnt drains. 64 KB LDS -> 2 blocks/CU.
// MAP=0: blockIdx=(col,row,ks) -> id%8=col%8 (colTiles%8==0)
// MAP=1: blockIdx=(ks,col,row) -> id%8=ks   (split-K XCD streams)
// ACT: 0 = f32 partial store at ks*csplit; 4 = bf16 store with bias.
// Kchunk must be a multiple of 64.
// ---------------------------------------------------------------------------
template<int ACT, int MAP>
__global__ __launch_bounds__(256, 2)
void gemm_bf16(const bf16_t* __restrict__ A, int lda,
               const bf16_t* __restrict__ Bt, int ldb,
               float* __restrict__ C, int ldc, size_t csplit,
               const float* __restrict__ bias,
               int M, int N, int K, int Kchunk)
{
  __shared__ __align__(16) bf16_t As[2][128*64];   // 2 x 16 KB
  __shared__ __align__(16) bf16_t Bs[2][128*64];   // 2 x 16 KB
  const int tid = threadIdx.x;
  const int w = tid >> 6, lane = tid & 63;
  const int wm = w >> 1, wn = w & 1;
  const int lr = lane & 15, kq = lane >> 4;
  int bcol, brow, bks;
  if (MAP == 0) { bcol = blockIdx.x; brow = blockIdx.y; bks = blockIdx.z; }
  else          { bks = blockIdx.x;  bcol = blockIdx.y; brow = blockIdx.z; }
  const int gm0 = brow * 128, gn0 = bcol * 128;
  const int k0 = bks * Kchunk;
  const int nt = (min(k0 + Kchunk, K) - k0) >> 6;   // K-slabs of 64

  // staging: unit u = tid + 256*j (j=0..3) for A and for B.
  // unit u -> row u>>3, slot u&7, source k-group (u&7)^(row&7), 8 bf16 wide.
  const bf16_t *pA0, *pA1, *pA2, *pA3, *pB0, *pB1, *pB2, *pB3;
  {
    const int u0 = tid, r_0 = u0 >> 3, g0 = (u0 & 7) ^ (r_0 & 7);
    const int u1 = tid + 256, r_1 = u1 >> 3, g1 = (u1 & 7) ^ (r_1 & 7);
    const int u2 = tid + 512, r_2 = u2 >> 3, g2 = (u2 & 7) ^ (r_2 & 7);
    const int u3 = tid + 768, r_3 = u3 >> 3, g3 = (u3 & 7) ^ (r_3 & 7);
    pA0 = A + (size_t)min(gm0 + r_0, M-1)*lda + k0 + g0*8;
    pA1 = A + (size_t)min(gm0 + r_1, M-1)*lda + k0 + g1*8;
    pA2 = A + (size_t)min(gm0 + r_2, M-1)*lda + k0 + g2*8;
    pA3 = A + (size_t)min(gm0 + r_3, M-1)*lda + k0 + g3*8;
    pB0 = Bt + (size_t)min(gn0 + r_0, N-1)*ldb + k0 + g0*8;
    pB1 = Bt + (size_t)min(gn0 + r_1, N-1)*ldb + k0 + g1*8;
    pB2 = Bt + (size_t)min(gn0 + r_2, N-1)*ldb + k0 + g2*8;
    pB3 = Bt + (size_t)min(gn0 + r_3, N-1)*ldb + k0 + g3*8;
  }
  bf16_t* Al = &As[0][0] + tid*8;    // unit j at elem tid*8 + j*2048
  bf16_t* Bl = &Bs[0][0] + tid*8;
  ushort8_t va0, va1, va2, va3, vb0, vb1, vb2, vb3;

#define LDT(t) do { \
    va0 = *(const ushort8_t*)(pA0 + (size_t)(t)*64); \
    va1 = *(const ushort8_t*)(pA1 + (size_t)(t)*64); \
    va2 = *(const ushort8_t*)(pA2 + (size_t)(t)*64); \
    va3 = *(const ushort8_t*)(pA3 + (size_t)(t)*64); \
    vb0 = *(const ushort8_t*)(pB0 + (size_t)(t)*64); \
    vb1 = *(const ushort8_t*)(pB1 + (size_t)(t)*64); \
    vb2 = *(const ushort8_t*)(pB2 + (size_t)(t)*64); \
    vb3 = *(const ushort8_t*)(pB3 + (size_t)(t)*64); \
  } while(0)
#define WRT(b) do { \
    *(ushort8_t*)(Al + (b)*8192)        = va0; \
    *(ushort8_t*)(Al + (b)*8192 + 2048) = va1; \
    *(ushort8_t*)(Al + (b)*8192 + 4096) = va2; \
    *(ushort8_t*)(Al + (b)*8192 + 6144) = va3; \
    *(ushort8_t*)(Bl + (b)*8192)        = vb0; \
    *(ushort8_t*)(Bl + (b)*8192 + 2048) = vb1; \
    *(ushort8_t*)(Bl + (b)*8192 + 4096) = vb2; \
    *(ushort8_t*)(Bl + (b)*8192 + 6144) = vb3; } while(0)

  LDT(0); WRT(0);
  if (nt > 1) LDT(1);
  asm volatile("s_waitcnt lgkmcnt(0)" ::: "memory");
  __builtin_amdgcn_s_barrier();
  __builtin_amdgcn_sched_barrier(0);

  const int ph = lr & 7;                     // XOR term for phys slot
  f32x4 acc[4][4] = {};

  for (int t = 0; t < nt; ++t) {
    const int cb = t & 1;
    const bf16_t* Ab = &As[0][0] + cb*8192;
    const bf16_t* Bb = &Bs[0][0] + cb*8192;
    bf16x8 af[2][4], bfr[2][4];
#pragma unroll
    for (int ks = 0; ks < 2; ks++) {
      const int phys = (ks*4 + kq) ^ ph;     // physical 16B slot
#pragma unroll
      for (int mi = 0; mi < 4; mi++)
        af[ks][mi] = *(const bf16x8*)(Ab + (wm*64 + mi*16 + lr)*64 + phys*8);
#pragma unroll
      for (int ni = 0; ni < 4; ni++)
        bfr[ks][ni] = *(const bf16x8*)(Bb + (wn*64 + ni*16 + lr)*64 + phys*8);
    }
    if (t + 1 < nt) WRT(cb ^ 1);     // tile t+1 (regs landed; auto vmcnt wait)
    if (t + 2 < nt) LDT(t + 2);      // issue loads for t+2
    __builtin_amdgcn_s_setprio(1);
#pragma unroll
    for (int ks = 0; ks < 2; ks++)
#pragma unroll
      for (int mi = 0; mi < 4; mi++)
#pragma unroll
        for (int ni = 0; ni < 4; ni++)
          acc[mi][ni] = __builtin_amdgcn_mfma_f32_16x16x32_bf16(af[ks][mi], bfr[ks][ni], acc[mi][ni], 0, 0, 0);
    __builtin_amdgcn_s_setprio(0);
    asm volatile("s_waitcnt lgkmcnt(0)" ::: "memory");
    __builtin_amdgcn_s_barrier();
    __builtin_amdgcn_sched_barrier(0);
  }
#undef LDT
#undef WRT

  // epilogue: D row = kq*4 + i, col = lane&15 per 16x16 frag
#pragma unroll
  for (int mi = 0; mi < 4; mi++) {
#pragma unroll
    for (int ni = 0; ni < 4; ni++) {
      const int col = gn0 + wn*64 + ni*16 + lr;
      const float bv = (ACT == 4) ? bias[col] : 0.f;
#pragma unroll
      for (int i = 0; i < 4; i++) {
        const int row = gm0 + wm*64 + mi*16 + kq*4 + i;
        if (row < M) {
          const float v = acc[mi][ni][i] + bv;
          if (ACT == 4) ((bf16_t*)C)[(size_t)row*ldc + col] = f2bf(v);
          else C[(size_t)bks*csplit + (size_t)row*ldc + col] = v;
        }
      }
    }
  }
}

// sum split-K partials, add bias, write prop f32 + X right half bf16
__global__ void reduce_compress(const float* __restrict__ part, const float* __restrict__ bias,
                                float* __restrict__ prop, bf16_t* __restrict__ xr)
{
  const int idx = blockIdx.x*256 + threadIdx.x;   // < 921600
  const int m = idx >> 10, d = idx & 1023;
  float v = bias[d];
#pragma unroll
  for (int z = 0; z < 8; z++) v += part[(size_t)z*921600 + idx];
  prop[idx] = v;
  xr[(size_t)m*2048 + 1024 + d] = f2bf(v);
}

// RZ split-2 reduce: v = sigmoid(p0+p1+bias). col<1024: Xh_right = bf16(v*prop)
// (the r path); col>=1024: Zbuf = v (the z path).
__global__ void reduce_rz(const float* __restrict__ part, const float* __restrict__ bias,
                          const float* __restrict__ prop, float* __restrict__ Zbuf,
                          bf16_t* __restrict__ Xh)
{
  const int idx = blockIdx.x*256 + threadIdx.x;   // < 1843200
  const int m = idx >> 11, c = idx & 2047;
  float v = part[idx] + part[1843200 + idx] + bias[c];
  v = 1.f / (1.f + __expf(-v));
  if (c < 1024) Xh[(size_t)m*2048 + 1024 + c] = f2bf(v * prop[(size_t)m*1024 + c]);
  else          Zbuf[(size_t)m*1024 + (c - 1024)] = v;
}

// h split-4 reduce: h_hat = tanh(sum+bh); prop = (1-z)*prop + z*h_hat;
// also write X right half bf16.
__global__ void reduce_h(const float* __restrict__ part, const float* __restrict__ bias,
                         const float* __restrict__ Zbuf, float* __restrict__ prop,
                         bf16_t* __restrict__ X)
{
  const int idx = blockIdx.x*256 + threadIdx.x;   // < 921600
  const int m = idx >> 10, d = idx & 1023;
  float v = bias[d];
#pragma unroll
  for (int z = 0; z < 4; z++) v += part[(size_t)z*921600 + idx];
  v = tanhf(v);
  const float zz = Zbuf[idx];
  const float pn = (1.f - zz)*prop[idx] + zz*v;
  prop[idx] = pn;
  X[(size_t)m*2048 + 1024 + d] = f2bf(pn);
}

// u_row[e][h] = sum_d W_edge[e][h][d]*W_att[e][d]; u_col with W_att[e][1024+d]
__global__ void compute_u(const float* __restrict__ We, const float* __restrict__ Wa,
                          float* __restrict__ u_row, float* __restrict__ u_col)
{
  const int w = threadIdx.x >> 6, lane = threadIdx.x & 63;
  const int idx = blockIdx.x*4 + w;               // grid=1792 -> idx<7168
  const int e = idx >> 10, h = idx & 1023;
  const float* wep = We + ((size_t)e*1024 + h)*1024;
  const float* wr  = Wa + (size_t)e*2048;
  const float* wc  = wr + 1024;
  float ar = 0.f, ac = 0.f;
#pragma unroll
  for (int t = 0; t < 16; t++) {
    const float v = wep[lane + 64*t];
    ar += v*wr[lane + 64*t];
    ac += v*wc[lane + 64*t];
  }
  for (int off = 32; off; off >>= 1) { ar += __shfl_down(ar, off); ac += __shfl_down(ac, off); }
  if (lane == 0) { u_row[idx] = ar; u_col[idx] = ac; }
}

// crc[e] = b_edge[e].Wa_row[e], crc[7+e] = b_edge[e].Wa_col[e]
__global__ void crc_kernel(const float* __restrict__ be, const float* __restrict__ Wa,
                           float* __restrict__ crc)
{
  const int w = threadIdx.x >> 6, lane = threadIdx.x & 63;
  for (int idx = w; idx < 14; idx += 4) {
    const int e = idx >> 1, which = idx & 1;
    const float* bp = be + e*1024;
    const float* wp = Wa + (size_t)e*2048 + which*1024;
    float a = 0.f;
#pragma unroll
    for (int t = 0; t < 16; t++) a += bp[lane + 64*t]*wp[lane + 64*t];
    for (int off = 32; off; off >>= 1) a += __shfl_down(a, off);
    if (lane == 0) crc[which*7 + e] = a;
  }
}

// per (b,e): row[n]=prop[b,n,:].u_row[e]; col[n]=prop[b,n,:].u_col[e]
// scores[b,e,i,j] = sigmoid(row[i]+col[j]+b_att[e]+crc_row[e]+crc_col[e])
__global__ void attn_kernel(const float* __restrict__ prop, const float* __restrict__ u_row,
                            const float* __restrict__ u_col, const float* __restrict__ crc,
                            const float* __restrict__ b_att, float* __restrict__ scores)
{
  const int b = blockIdx.x, e = blockIdx.y;
  __shared__ float rowv[15], colv[15];
  const int w = threadIdx.x >> 6, lane = threadIdx.x & 63;
  const float* ur = u_row + (size_t)e*1024;
  const float* uc = u_col + (size_t)e*1024;
  for (int n = w; n < 15; n += 4) {
    const float* pr = prop + (size_t)(b*15 + n)*1024;
    float ar = 0.f, ac = 0.f;
#pragma unroll
    for (int t = 0; t < 16; t++) {
      const float pv = pr[lane + 64*t];
      ar += pv*ur[lane + 64*t];
      ac += pv*uc[lane + 64*t];
    }
    for (int off = 32; off; off >>= 1) { ar += __shfl_down(ar, off); ac += __shfl_down(ac, off); }
    if (lane == 0) { rowv[n] = ar; colv[n] = ac; }
  }
  __syncthreads();
  const float base = b_att[e] + crc[e] + crc[7 + e];
  for (int idx = threadIdx.x; idx < 225; idx += 256) {
    const int i = idx/15, j = idx - i*15;
    const float s = 1.f / (1.f + __expf(-(rowv[i] + colv[j] + base)));
    scores[((size_t)(b*7 + e)*15 + i)*15 + j] = s;
  }
}

// merged[b,i,d] = sum_e sum_j scores[b,e,i,j]*msg[b*15+j, e*1024+d]
// -> X left half AND Xh left half (bf16)
__global__ void merged_kernel(const bf16_t* __restrict__ msg, const float* __restrict__ scores,
                              bf16_t* __restrict__ X, bf16_t* __restrict__ Xh)
{
  const int b = blockIdx.x, c = blockIdx.y;   // c: 128-wide d-chunk, 8 chunks
  __shared__ float ms[15*7*128];              // [j][e][dl]
  __shared__ float sc[1575];                  // [e][i][j]
  for (int q = threadIdx.x; q < 3360; q += 256) {     // 4-wide bf16 loads
    const int idx = q*4;
    const int j = idx / 896;
    const int rem = idx - j*896;
    const int e = rem >> 7, dl = rem & 127;
    const ushort4 v = *(const ushort4*)(msg + (size_t)(b*15 + j)*7168 + e*1024 + c*128 + dl);
    ms[idx]   = bf2f(v.x);
    ms[idx+1] = bf2f(v.y);
    ms[idx+2] = bf2f(v.z);
    ms[idx+3] = bf2f(v.w);
  }
  for (int idx = threadIdx.x; idx < 1575; idx += 256)
    sc[idx] = scores[(size_t)b*1575 + idx];
  __syncthreads();
  for (int oi = threadIdx.x; oi < 1920; oi += 256) {
    const int i = oi >> 7, dl = oi & 127;
    float acc = 0.f;
#pragma unroll
    for (int e = 0; e < 7; e++)
#pragma unroll
      for (int j = 0; j < 15; j++)
        acc += sc[(e*15 + i)*15 + j] * ms[j*896 + e*128 + dl];
    const bf16_t o = f2bf(acc);
    X [(size_t)(b*15 + i)*2048 + c*128 + dl] = o;
    Xh[(size_t)(b*15 + i)*2048 + c*128 + dl] = o;
  }
}

// 64x64-tile transpose f32 -> bf16: out[c][r] = in[r][c]  (dims %64 == 0)
__global__ void transpose_k(const float* __restrict__ in, bf16_t* __restrict__ out,
                            int R, int C, int out_ld, size_t in_batch, size_t out_batch)
{
  __shared__ float t[64][65];
  in  += (size_t)blockIdx.z * in_batch;
  out += (size_t)blockIdx.z * out_batch;
  const int r0 = blockIdx.x*64, c0 = blockIdx.y*64;
  const int tc = threadIdx.x & 63, tr = threadIdx.x >> 6;
#pragma unroll
  for (int i = 0; i < 16; i++) {
    const int r = tr*16 + i;
    t[r][tc] = in[(size_t)(r0 + r)*C + c0 + tc];
  }
  __syncthreads();
#pragma unroll
  for (int i = 0; i < 16; i++) {
    const int rr = tr*16 + i;
    out[(size_t)(c0 + rr)*out_ld + r0 + tc] = f2bf(t[tc][rr]);
  }
}

__global__ void cast_f32_bf16(const float4* __restrict__ in, ushort4* __restrict__ out, int n4)
{
  int i = blockIdx.x*256 + threadIdx.x;
  const int stride = gridDim.x*256;
  for (; i < n4; i += stride) {
    const float4 v = in[i];
    out[i] = make_ushort4(f2bf(v.x), f2bf(v.y), f2bf(v.z), f2bf(v.w));
  }
}

__global__ void cat2_kernel(const float* __restrict__ a, const float* __restrict__ b,
                            float* __restrict__ o)
{
  const int i = blockIdx.x*256 + threadIdx.x;
  if (i < 1024) o[i] = a[i];
  else if (i < 2048) o[i] = b[i - 1024];
}

// final outputs from last-iteration scores
__global__ void finalize_kernel(const float* __restrict__ scores, float* __restrict__ out)
{
  const int b = blockIdx.x;   // 0..59
  __shared__ float sc[1575];
  __shared__ float act[105];
  __shared__ float asum[15];
  __shared__ float t2[7];
  for (int idx = threadIdx.x; idx < 1575; idx += 256)
    sc[idx] = scores[(size_t)b*1575 + idx];
  __syncthreads();
  for (int idx = threadIdx.x; idx < 105; idx += 256) {
    const int i = idx/7, e = idx - i*7;
    float a = 0.f;
#pragma unroll
    for (int j = 0; j < 15; j++)
      a += (1.f - sc[i*15 + j]) * sc[(e*15 + i)*15 + j];
    act[idx] = a;
    out[(size_t)b*105 + idx] = a;
  }
  for (int idx = threadIdx.x; idx < 225; idx += 256) {
    const int i = idx/15, j = idx - i*15;
    out[6660 + (size_t)b*225 + idx] = 1.f - sc[i*15 + j];
  }
  if (threadIdx.x < 15) {
    const int i = threadIdx.x;
    float s = 0.f;
#pragma unroll
    for (int j = 0; j < 15; j++) s += 1.f - sc[i*15 + j];
    asum[i] = s;
  }
  __syncthreads();
  if (threadIdx.x < 7) {
    const int e = threadIdx.x;
    float t = 0.f;
#pragma unroll
    for (int i = 0; i < 15; i++) t += act[i*7 + e]*asum[i];
    t2[e] = t;
  }
  __syncthreads();
  if (threadIdx.x == 0) {
    float mx = -1e30f;
    for (int e = 1; e < 7; e++) mx = fmaxf(mx, t2[e]);
    float s = 0.f, ex[6];
    for (int e = 1; e < 7; e++) { ex[e-1] = __expf(t2[e] - mx); s += ex[e-1]; }
    for (int e = 1; e < 7; e++) out[6300 + (size_t)b*6 + (e-1)] = ex[e-1]/s;
  }
}

extern "C" void kernel_launch(void* const* d_in, const int* in_sizes, int n_in,
                              void* d_out, int out_size, void* d_ws, size_t ws_size,
                              hipStream_t stream)
{
  const float* pose = (const float*)d_in[0];
  const float* Wc   = (const float*)d_in[1];
  const float* bc   = (const float*)d_in[2];
  const float* We   = (const float*)d_in[3];
  const float* be   = (const float*)d_in[4];
  const float* Wa   = (const float*)d_in[5];
  const float* ba   = (const float*)d_in[6];
  const float* Wr   = (const float*)d_in[7];
  const float* br   = (const float*)d_in[8];
  const float* Wz   = (const float*)d_in[9];
  const float* bz   = (const float*)d_in[10];
  const float* Wh   = (const float*)d_in[11];
  const float* bh   = (const float*)d_in[12];
  float* out = (float*)d_out;

  // ---- workspace carving ----
  char* p = (char*)d_ws;
  auto alloc = [&](size_t b) { char* r = p; p += (b + 255) & ~(size_t)255; return r; };
  bf16_t* Wedge_t = (bf16_t*)alloc(7168ull*1024*2);   // [e*1024+d][h]
  bf16_t* Wrz_t   = (bf16_t*)alloc(2048ull*2048*2);   // [n][k]
  bf16_t* Wh_t    = (bf16_t*)alloc(1024ull*2048*2);   // [n][k]
  bf16_t* X       = (bf16_t*)alloc(900ull*2048*2);    // [merged | prop] bf16
  float*  prop    = (float*) alloc(900ull*1024*4);    // f32 master state
  float*  scores  = (float*) alloc(60ull*7*15*15*4);
  float*  u_row   = (float*) alloc(7168*4);
  float*  u_col   = (float*) alloc(7168*4);
  float*  crc     = (float*) alloc(64);
  float*  brzv    = (float*) alloc(2048*4);
  // phase-union region:
  // phase1 (compress): Abf(46.08) + Wct(52.43) + partial(29.49) = 128 MB
  // phase2 (iters): msgb 12.9 | Zbuf 3.69 | Xh 3.69 | partRZ 29.5 | partH 14.7
  char* r1 = alloc(128000000ull);
  bf16_t* Abf     = (bf16_t*)r1;
  bf16_t* Wct     = (bf16_t*)(r1 + 46080000ull);
  float*  partial = (float*) (r1 + 46080000ull + 52428800ull);
  bf16_t* msgb    = (bf16_t*)r1;
  float*  Zbuf    = (float*) (r1 + 12902400ull);
  bf16_t* Xh      = (bf16_t*)(r1 + 16588800ull);
  float*  partRZ  = (float*) (r1 + 20275200ull);      // 2 x 900 x 2048 f32
  float*  partH   = (float*) (r1 + 49766400ull);      // 4 x 900 x 1024 f32

  // ---- precompute ----
  compute_u<<<1792, 256, 0, stream>>>(We, Wa, u_row, u_col);
  crc_kernel<<<1, 256, 0, stream>>>(be, Wa, crc);
  cast_f32_bf16<<<2048, 256, 0, stream>>>((const float4*)pose, (ushort4*)Abf, 23040000/4);
  transpose_k<<<dim3(400,16,1), 256, 0, stream>>>(Wc, Wct, 25600, 1024, 25600, 0, 0);
  transpose_k<<<dim3(16,16,7),  256, 0, stream>>>(We, Wedge_t, 1024, 1024, 1024,
                                                  1024ull*1024, 1024ull*1024);
  transpose_k<<<dim3(32,16,1),  256, 0, stream>>>(Wr, Wrz_t, 2048, 1024, 2048, 0, 0);
  transpose_k<<<dim3(32,16,1),  256, 0, stream>>>(Wz, Wrz_t + 1024ull*2048, 2048, 1024, 2048, 0, 0);
  transpose_k<<<dim3(32,16,1),  256, 0, stream>>>(Wh, Wh_t, 2048, 1024, 2048, 0, 0);
  cat2_kernel<<<8, 256, 0, stream>>>(br, bz, brzv);

  // compress: prop = pose @ W_compress + b_compress
  // 128x128 tiles: 8 cols x 8 rows x ks=8 (MAP1, id%8=ks) = 512 blocks, nt=50
  gemm_bf16<0,1><<<dim3(8,8,8), 256, 0, stream>>>(Abf, 25600, Wct, 25600,
      partial, 1024, 921600ull, nullptr, 900, 1024, 25600, 3200);
  reduce_compress<<<3600, 256, 0, stream>>>(partial, bc, prop, X);

  // ---- 6 recurrent iterations (last one: scores only) ----
  for (int it = 0; it < 6; it++) {
    attn_kernel<<<dim3(60,7), 256, 0, stream>>>(prop, u_row, u_col, crc, ba, scores);
    if (it == 5) break;
    // msg = prop @ W_edge + b_edge  (56 col-tiles x 8 rows = 448 blocks,
    // id%8 = col%8, nt=16)
    gemm_bf16<4,0><<<dim3(56,8,1), 256, 0, stream>>>(X + 1024, 2048, Wedge_t, 1024,
        (float*)msgb, 7168, 0, be, 900, 7168, 1024, 1024);
    merged_kernel<<<dim3(60,8), 256, 0, stream>>>(msgb, scores, X, Xh);
    // [r|z] partials = X @ [Wr|Wz]  (16 cols x 8 rows x ks=2 = 256, nt=16)
    gemm_bf16<0,0><<<dim3(16,8,2), 256, 0, stream>>>(X, 2048, Wrz_t, 2048,
        partRZ, 2048, 1843200ull, nullptr, 900, 2048, 2048, 1024);
    reduce_rz<<<7200, 256, 0, stream>>>(partRZ, brzv, prop, Zbuf, Xh);
    // h partials = Xh @ Wh  (8 cols x 8 rows x ks=4 = 256 blocks, nt=8)
    gemm_bf16<0,0><<<dim3(8,8,4), 256, 0, stream>>>(Xh, 2048, Wh_t, 2048,
        partH, 1024, 921600ull, nullptr, 900, 1024, 2048, 512);
    reduce_h<<<3600, 256, 0, stream>>>(partH, bh, Zbuf, prop, X);
  }

  finalize_kernel<<<60, 256, 0, stream>>>(scores, out);
}